// Round 14
// baseline (1418.138 us; speedup 1.0000x reference)
//
#include <hip/hip_runtime.h>
#include <cstdint>

#define NSRV 10000
#define NDEV 50000
#define HDIM 512
#define NEDGE 300000
#define NLAY 4
#define SCHUNK 2048
#define NCH_D ((NDEV + SCHUNK - 1) / SCHUNK)  // 25
#define NCH_S ((NSRV + SCHUNK - 1) / SCHUNK)  // 5

typedef unsigned int u32;
typedef unsigned short u16;

typedef __bf16 bf16x8 __attribute__((ext_vector_type(8)));
typedef float f32x4 __attribute__((ext_vector_type(4)));

// ---------- bf16 helpers ----------
__device__ __forceinline__ float bflo(u32 u) { return __uint_as_float(u << 16); }
__device__ __forceinline__ float bfhi(u32 u) { return __uint_as_float(u & 0xffff0000u); }
__device__ __forceinline__ float bf2f(u16 v) { return __uint_as_float((u32)v << 16); }
__device__ __forceinline__ u16 f2bf(float f) {
    u32 u = __float_as_uint(f);
    u += 0x7fffu + ((u >> 16) & 1u);  // RNE
    return (u16)(u >> 16);
}
__device__ __forceinline__ u32 pack2(float a, float b) {
    return (u32)f2bf(a) | ((u32)f2bf(b) << 16);
}

// ---------- f32 -> bf16 cast ----------
__global__ void cast_bf16(const float* __restrict__ src, u16* __restrict__ dst, int n2) {
    int i = blockIdx.x * 256 + threadIdx.x;
    if (i < n2) {
        float2 v = *(const float2*)(src + 2 * (size_t)i);
        *(u32*)(dst + 2 * (size_t)i) = pack2(v.x, v.y);
    }
}

// ---------- weight transpose + bf16 cast (512x512 x16 matrices) ----------
__global__ void transpose_w(const float* __restrict__ Wl, const float* __restrict__ Wr,
                            u16* __restrict__ WlT, u16* __restrict__ WrT) {
    __shared__ float t[32][33];
    int z = blockIdx.z;
    const float* Wsrc = ((z < 8) ? Wl : Wr) + (size_t)(z & 7) * HDIM * HDIM;
    u16* Wdst = ((z < 8) ? WlT : WrT) + (size_t)(z & 7) * HDIM * HDIM;
    int n0 = blockIdx.x * 32, k0 = blockIdx.y * 32;
    int x = threadIdx.x, y = threadIdx.y;
#pragma unroll
    for (int i = 0; i < 4; ++i)
        t[y + 8 * i][x] = Wsrc[(size_t)(k0 + y + 8 * i) * HDIM + n0 + x];
    __syncthreads();
    if (x < 16) {
#pragma unroll
        for (int i = 0; i < 4; ++i) {
            int n = n0 + y + 8 * i;
            u32 v = pack2(t[2 * x][y + 8 * i], t[2 * x + 1][y + 8 * i]);
            *(u32*)(Wdst + (size_t)n * HDIM + k0 + 2 * x) = v;
        }
    }
}

// ---------- proj weight transpose: W[K][512] f32 -> WT[512][K] bf16 ----------
template <int K>
__global__ void transpose_wp(const float* __restrict__ W, u16* __restrict__ WT) {
    __shared__ float t[32][33];
    int n0 = blockIdx.x * 32, k0 = blockIdx.y * 32;
    int x = threadIdx.x, y = threadIdx.y;
#pragma unroll
    for (int i = 0; i < 4; ++i)
        t[y + 8 * i][x] = W[(size_t)(k0 + y + 8 * i) * HDIM + n0 + x];
    __syncthreads();
    if (x < 16) {
#pragma unroll
        for (int i = 0; i < 4; ++i) {
            int n = n0 + y + 8 * i;
            u32 v = pack2(t[2 * x][y + 8 * i], t[2 * x + 1][y + 8 * i]);
            *(u32*)(WT + (size_t)n * K + k0 + 2 * x) = v;
        }
    }
}

// ---------- MFMA projection ----------
template <int KTOT>
__launch_bounds__(256, 2)
__global__ void proj_gemm(const u16* __restrict__ A, const u16* __restrict__ B,
                          const float* __restrict__ bias, u16* __restrict__ C, int M) {
    constexpr int NKC = KTOT / 8;
    __shared__ __align__(16) u16 As[NKC][128][8];
    __shared__ __align__(16) u16 Bs[NKC][128][8];
    const int tid = threadIdx.x;
    const int lane = tid & 63;
    const int w = tid >> 6;
    const int m0 = blockIdx.x * 128, n0 = blockIdx.y * 128;
    const int wm = w >> 1, wn = w & 1;
    const int g = lane >> 4, r = lane & 15;

    for (int idx = tid; idx < NKC * 128; idx += 256) {
        int row = idx / NKC, kc = idx % NKC;
        int ra = m0 + row; if (ra > M - 1) ra = M - 1;
        *(uint4*)&As[kc][row][0] = *(const uint4*)(A + (size_t)ra * KTOT + kc * 8);
        *(uint4*)&Bs[kc][row][0] = *(const uint4*)(B + (size_t)(n0 + row) * KTOT + kc * 8);
    }
    __syncthreads();

    f32x4 acc[4][4];
#pragma unroll
    for (int i = 0; i < 4; ++i)
#pragma unroll
        for (int j = 0; j < 4; ++j) acc[i][j] = (f32x4){0.f, 0.f, 0.f, 0.f};

#pragma unroll
    for (int t = 0; t < KTOT / 32; ++t) {
        bf16x8 af[4], bfr[4];
#pragma unroll
        for (int i = 0; i < 4; ++i) {
            af[i]  = *(const bf16x8*)&As[t * 4 + g][wm * 64 + i * 16 + r][0];
            bfr[i] = *(const bf16x8*)&Bs[t * 4 + g][wn * 64 + i * 16 + r][0];
        }
#pragma unroll
        for (int i = 0; i < 4; ++i)
#pragma unroll
            for (int j = 0; j < 4; ++j)
                acc[i][j] = __builtin_amdgcn_mfma_f32_16x16x32_bf16(af[i], bfr[j], acc[i][j], 0, 0, 0);
    }
    __syncthreads();

    float bv[4];
#pragma unroll
    for (int j = 0; j < 4; ++j) bv[j] = bias[n0 + wn * 64 + j * 16 + r];

    u16* ep = ((u16*)As) + w * 1024;
    const int rr = lane >> 3;
    const int cc = (lane & 7) * 8;
#pragma unroll
    for (int i = 0; i < 4; ++i) {
#pragma unroll
        for (int j = 0; j < 4; ++j)
#pragma unroll
            for (int q = 0; q < 4; ++q)
                ep[(g * 4 + q) * 64 + j * 16 + r] = f2bf(acc[i][j][q] + bv[j]);
        __syncthreads();
        int row0 = m0 + wm * 64 + i * 16 + rr;
        int row1 = row0 + 8;
        uint4 v0 = *(uint4*)&ep[rr * 64 + cc];
        uint4 v1 = *(uint4*)&ep[(rr + 8) * 64 + cc];
        if (row0 < M) *(uint4*)(C + (size_t)row0 * HDIM + n0 + wn * 64 + cc) = v0;
        if (row1 < M) *(uint4*)(C + (size_t)row1 * HDIM + n0 + wn * 64 + cc) = v1;
        __syncthreads();
    }
}

// ---------- CSR build ----------
__global__ void count_k(const int* __restrict__ d_sd, const int* __restrict__ d_ds,
                        int* __restrict__ cd, int* __restrict__ cs) {
    int i = blockIdx.x * 256 + threadIdx.x;
    if (i < NEDGE) atomicAdd(&cd[d_sd[i]], 1);
    else if (i < 2 * NEDGE) atomicAdd(&cs[d_ds[i - NEDGE]], 1);
}

__global__ void scan_a_both(const int* __restrict__ cd, int* __restrict__ od, int* __restrict__ csd,
                            const int* __restrict__ cs, int* __restrict__ os, int* __restrict__ css) {
    __shared__ int wsum[4];
    int blk = blockIdx.x;
    const int* c; int* o; int* csum; int n; int cb;
    if (blk < NCH_D) { c = cd; o = od; csum = csd; n = NDEV; cb = blk; }
    else             { c = cs; o = os; csum = css; n = NSRV; cb = blk - NCH_D; }
    int tid = threadIdx.x;
    int base = cb * SCHUNK;
    int idx0 = base + tid * 8;
    int v[8];
    int s = 0;
#pragma unroll
    for (int i = 0; i < 8; ++i) {
        int idx = idx0 + i;
        v[i] = (idx < n) ? c[idx] : 0;
        s += v[i];
    }
    int lane = tid & 63, wv = tid >> 6;
    int ss = s;
#pragma unroll
    for (int off = 1; off < 64; off <<= 1) {
        int t = __shfl_up(ss, off);
        if (lane >= off) ss += t;
    }
    if (lane == 63) wsum[wv] = ss;
    __syncthreads();
    int woff = 0;
#pragma unroll
    for (int i = 0; i < 4; ++i)
        if (i < wv) woff += wsum[i];
    int ex = woff + ss - s;
#pragma unroll
    for (int i = 0; i < 8; ++i) {
        int idx = idx0 + i;
        if (idx < n) o[idx] = ex;
        ex += v[i];
    }
    if (tid == 255) csum[cb] = woff + ss;
}

__global__ void scan_k(const int* __restrict__ cA, int* __restrict__ oA, int* __restrict__ uA, int nA,
                       const int* __restrict__ cB, int* __restrict__ oB, int* __restrict__ uB, int nB) {
    const int* c; int* o; int* u; int n;
    if (blockIdx.x == 0) { c = cA; o = oA; u = uA; n = nA; }
    else                 { c = cB; o = oB; u = uB; n = nB; }
    int lane = threadIdx.x;
    int carry = 0;
    for (int base = 0; base < n; base += 64) {
        int idx = base + lane;
        int v = (idx < n) ? c[idx] : 0;
        int s = v;
#pragma unroll
        for (int off = 1; off < 64; off <<= 1) {
            int t = __shfl_up(s, off);
            if (lane >= off) s += t;
        }
        if (idx < n) { int ex = carry + s - v; o[idx] = ex; u[idx] = ex; }
        carry += __shfl(s, 63);
    }
}

__global__ void scan_c_both(int* __restrict__ od, int* __restrict__ curd, const int* __restrict__ csxd,
                            int* __restrict__ os, int* __restrict__ curs, const int* __restrict__ csxs) {
    int i = blockIdx.x * 256 + threadIdx.x;
    if (i < NDEV) {
        int v = od[i] + csxd[i / SCHUNK];
        od[i] = v;
        curd[i] = v;
    } else if (i < NDEV + NSRV) {
        int j = i - NDEV;
        int v = os[j] + csxs[j / SCHUNK];
        os[j] = v;
        curs[j] = v;
    }
}

__global__ void fill_k(const int* __restrict__ s_sd, const int* __restrict__ d_sd,
                       int* __restrict__ cur_d, int* __restrict__ srcs_d,
                       const int* __restrict__ s_ds, const int* __restrict__ d_ds,
                       int* __restrict__ cur_s, int* __restrict__ srcs_s) {
    int i = blockIdx.x * 256 + threadIdx.x;
    if (i < NEDGE) {
        int p = atomicAdd(&cur_d[d_sd[i]], 1);
        srcs_d[p] = s_sd[i];
    } else if (i < 2 * NEDGE) {
        int j = i - NEDGE;
        int p = atomicAdd(&cur_s[d_ds[j]], 1);
        srcs_s[p] = s_ds[j];
    }
}

// ---------- fused scatter-mean, 8-wide MLP ----------
__global__ void aggregate_both(const u16* __restrict__ hs, const u16* __restrict__ hd,
                               const int* __restrict__ offs_d, const int* __restrict__ cnt_d,
                               const int* __restrict__ src_d,
                               const int* __restrict__ offs_s, const int* __restrict__ cnt_s,
                               const int* __restrict__ src_s,
                               u16* __restrict__ agg_d, u16* __restrict__ agg_s) {
    int wv = threadIdx.x >> 6, lane = threadIdx.x & 63;
    int d = blockIdx.x * 4 + wv;
    const u16* h; const int* offs; const int* cnt; const int* srcs; u16* agg; int idx;
    if (d < NDEV)              { h = hs; offs = offs_d; cnt = cnt_d; srcs = src_d; agg = agg_d; idx = d; }
    else if (d < NDEV + NSRV)  { h = hd; offs = offs_s; cnt = cnt_s; srcs = src_s; agg = agg_s; idx = d - NDEV; }
    else return;
    int beg = offs[idx], deg = cnt[idx];
    float acc[8] = {0.f, 0.f, 0.f, 0.f, 0.f, 0.f, 0.f, 0.f};
    const size_t lanecol = (size_t)lane * 8;
    auto accum = [&](const uint4& q) {
        acc[0] += bflo(q.x); acc[1] += bfhi(q.x);
        acc[2] += bflo(q.y); acc[3] += bfhi(q.y);
        acc[4] += bflo(q.z); acc[5] += bfhi(q.z);
        acc[6] += bflo(q.w); acc[7] += bfhi(q.w);
    };
    for (int t0 = 0; t0 < deg; t0 += 64) {
        int nch = min(64, deg - t0);
        int sv = (t0 + lane < deg) ? srcs[beg + t0 + lane] : 0;
        int j = 0;
        for (; j + 8 <= nch; j += 8) {  // 8 independent row-gathers in flight
            uint4 q[8];
#pragma unroll
            for (int u_ = 0; u_ < 8; ++u_) {
                int s = __shfl(sv, j + u_);
                q[u_] = *(const uint4*)(h + (size_t)s * HDIM + lanecol);
            }
#pragma unroll
            for (int u_ = 0; u_ < 8; ++u_) accum(q[u_]);
        }
        for (; j + 4 <= nch; j += 4) {
            uint4 q[4];
#pragma unroll
            for (int u_ = 0; u_ < 4; ++u_) {
                int s = __shfl(sv, j + u_);
                q[u_] = *(const uint4*)(h + (size_t)s * HDIM + lanecol);
            }
#pragma unroll
            for (int u_ = 0; u_ < 4; ++u_) accum(q[u_]);
        }
        for (; j < nch; ++j) {
            int s = __shfl(sv, j);
            const uint4 q = *(const uint4*)(h + (size_t)s * HDIM + lanecol);
            accum(q);
        }
    }
    float sc = 1.f / (float)(deg > 0 ? deg : 1);
    uint4 o;
    o.x = pack2(acc[0] * sc, acc[1] * sc);
    o.y = pack2(acc[2] * sc, acc[3] * sc);
    o.z = pack2(acc[4] * sc, acc[5] * sc);
    o.w = pack2(acc[6] * sc, acc[7] * sc);
    *(uint4*)(agg + (size_t)idx * HDIM + lanecol) = o;
}

// ---------- fused SAGE GEMM 256x128, dev + srv segments, 2-deep prefetch ----------
// Tile t's staged registers live in regset t&1; at iter kt we issue gload(kt+2),
// swrite(kt+1) (loads issued a full iteration ago -> vmcnt wait ~free), compute(kt).
// One barrier per iter (unchanged sync structure); math order identical.
__launch_bounds__(512, 2)
__global__ void gemm_both(const u16* __restrict__ A1d, const u16* __restrict__ A2d,
                          const u16* __restrict__ B1d, const u16* __restrict__ B2d,
                          const float* __restrict__ bd, u16* __restrict__ Cd, int Md, int MBd, int GD,
                          const u16* __restrict__ A1s, const u16* __restrict__ A2s,
                          const u16* __restrict__ B1s, const u16* __restrict__ B2s,
                          const float* __restrict__ bs, u16* __restrict__ Cs, int Ms, int MBs) {
    int b = blockIdx.x;
    const u16 *A1, *A2, *B1, *B2; const float* bias; u16* C; int M, MB;
    if (b < GD) { A1 = A1d; A2 = A2d; B1 = B1d; B2 = B2d; bias = bd; C = Cd; M = Md; MB = MBd; }
    else { b -= GD; A1 = A1s; A2 = A2s; B1 = B1s; B2 = B2s; bias = bs; C = Cs; M = Ms; MB = MBs; }
    const int mi = (b >> 5) * 8 + (b & 7);
    const int ni = (b >> 3) & 3;
    if (mi >= MB) return;

    __shared__ __align__(16) u16 As[2][4][256][8];  // 32 KB
    __shared__ __align__(16) u16 Bs[2][4][128][8];  // 16 KB
    const int tid = threadIdx.x;
    const int lane = tid & 63;
    const int w = tid >> 6;
    const int m0 = mi * 256, n0 = ni * 128;
    const int wm = w >> 1, wn = w & 1;
    const int g = lane >> 4, r = lane & 15;

    const int srow = tid >> 2;          // 0..127
    const int skc  = tid & 3;           // 0..3

    f32x4 acc[4][4];
#pragma unroll
    for (int i = 0; i < 4; ++i)
#pragma unroll
        for (int j = 0; j < 4; ++j) acc[i][j] = (f32x4){0.f, 0.f, 0.f, 0.f};

    uint4 ra0[2], ra1[2], rb0[2];  // 2-deep prefetch register sets
    auto gload = [&](int set, int kt) {
        const u16* Ap = (kt < 16) ? A1 : A2;
        const u16* Bp = (kt < 16) ? B1 : B2;
        const int kb = (kt & 15) * 32 + skc * 8;
        int r0 = m0 + srow;       if (r0 > M - 1) r0 = M - 1;
        int r1 = m0 + srow + 128; if (r1 > M - 1) r1 = M - 1;
        ra0[set] = *(const uint4*)(Ap + (size_t)r0 * HDIM + kb);
        ra1[set] = *(const uint4*)(Ap + (size_t)r1 * HDIM + kb);
        rb0[set] = *(const uint4*)(Bp + (size_t)(n0 + srow) * HDIM + kb);
    };
    auto swrite = [&](int buf, int set) {
        *(uint4*)&As[buf][skc][srow][0]       = ra0[set];
        *(uint4*)&As[buf][skc][srow + 128][0] = ra1[set];
        *(uint4*)&Bs[buf][skc][srow][0]       = rb0[set];
    };
    auto compute = [&](int buf) {
        bf16x8 af[4], bfr[4];
#pragma unroll
        for (int i = 0; i < 4; ++i) {
            af[i]  = *(const bf16x8*)&As[buf][g][wm * 64 + i * 16 + r][0];
            bfr[i] = *(const bf16x8*)&Bs[buf][g][wn * 64 + i * 16 + r][0];
        }
#pragma unroll
        for (int i = 0; i < 4; ++i)
#pragma unroll
            for (int j = 0; j < 4; ++j)
                acc[i][j] = __builtin_amdgcn_mfma_f32_16x16x32_bf16(af[i], bfr[j], acc[i][j], 0, 0, 0);
    };

    // prologue: tile t -> set[t&1]
    gload(0, 0);
    swrite(0, 0);
    gload(1, 1);
    __syncthreads();
    for (int kt = 0; kt < 32; ++kt) {
        if (kt + 2 < 32) gload(kt & 1, kt + 2);       // 2 ahead, reuses consumed set
        if (kt + 1 < 32) swrite((kt + 1) & 1, (kt + 1) & 1);  // loads from iter kt-1
        compute(kt & 1);
        __syncthreads();
    }

    // epilogue: 2 i-blocks per LDS staging round
    float bv[4];
#pragma unroll
    for (int j = 0; j < 4; ++j) bv[j] = bias[n0 + wn * 64 + j * 16 + r];

    u16* ep = ((u16*)As) + w * 2048;
    const int rr = lane >> 3;
    const int cc = (lane & 7) * 8;
#pragma unroll
    for (int ih = 0; ih < 2; ++ih) {
#pragma unroll
        for (int ii = 0; ii < 2; ++ii) {
            int i = ih * 2 + ii;
#pragma unroll
            for (int j = 0; j < 4; ++j)
#pragma unroll
                for (int q = 0; q < 4; ++q)
                    ep[ii * 1024 + (g * 4 + q) * 64 + j * 16 + r] =
                        f2bf(fmaxf(acc[i][j][q] + bv[j], 0.f));
        }
        __syncthreads();
#pragma unroll
        for (int ii = 0; ii < 2; ++ii) {
            int i = ih * 2 + ii;
            int row0 = m0 + wm * 64 + i * 16 + rr;
            int row1 = row0 + 8;
            uint4 v0 = *(uint4*)&ep[ii * 1024 + rr * 64 + cc];
            uint4 v1 = *(uint4*)&ep[ii * 1024 + (rr + 8) * 64 + cc];
            if (row0 < M) *(uint4*)(C + (size_t)row0 * HDIM + n0 + wn * 64 + cc) = v0;
            if (row1 < M) *(uint4*)(C + (size_t)row1 * HDIM + n0 + wn * 64 + cc) = v1;
        }
        __syncthreads();
    }
}

// ---------- in-place bf16 -> f32 widening of d_out ----------
__global__ void expand_k(float* out, int lo, int hi) {
    const u16* src = (const u16*)out;
    int j = lo + blockIdx.x * 256 + threadIdx.x;
    if (j < hi) {
        float v = bf2f(src[j]);
        out[(size_t)j] = v;
    }
}
__global__ void expand_final(float* out, int n) {
    __shared__ u16 tmp[4096];
    const u16* src = (const u16*)out;
    int tid = threadIdx.x;
    for (int i = tid; i < n; i += blockDim.x) tmp[i] = src[i];
    __syncthreads();
    for (int i = tid; i < n; i += blockDim.x) out[(size_t)i] = bf2f(tmp[i]);
}

// ---------- host orchestration ----------
extern "C" void kernel_launch(void* const* d_in, const int* in_sizes, int n_in,
                              void* d_out, int out_size, void* d_ws, size_t ws_size,
                              hipStream_t stream) {
    const float* x_s   = (const float*)d_in[0];
    const float* x_d   = (const float*)d_in[1];
    const float* W_srv = (const float*)d_in[2];
    const float* b_srv = (const float*)d_in[3];
    const float* W_dev = (const float*)d_in[4];
    const float* b_dev = (const float*)d_in[5];
    const float* Wl    = (const float*)d_in[6];
    const float* bl    = (const float*)d_in[7];
    const float* Wr    = (const float*)d_in[8];
    const int* e_sd_src = (const int*)d_in[9];
    const int* e_sd_dst = (const int*)d_in[10];
    const int* e_ds_src = (const int*)d_in[11];
    const int* e_ds_dst = (const int*)d_in[12];

    const size_t NTOT = (size_t)(NSRV + NDEV) * HDIM;
    float* fout = (float*)d_out;
    u16* u = (u16*)d_out;
    u16* hA_s = u;
    u16* hA_d = u + (size_t)NSRV * HDIM;
    u16* hB_s = u + NTOT;
    u16* hB_d = u + NTOT + (size_t)NSRV * HDIM;

    char* p = (char*)d_ws;
    auto carve = [&](size_t bytes) -> void* {
        void* ret = (void*)p;
        p += (bytes + 255) & ~(size_t)255;
        return ret;
    };
    int* cnt_d = (int*)carve((size_t)NDEV * 4);
    int* cnt_s = (int*)carve((size_t)NSRV * 4);
    int* off_d = (int*)carve((size_t)NDEV * 4);
    int* off_s = (int*)carve((size_t)NSRV * 4);
    int* cur_d = (int*)carve((size_t)NDEV * 4);
    int* cur_s = (int*)carve((size_t)NSRV * 4);
    int* src_d = (int*)carve((size_t)NEDGE * 4);
    int* src_s = (int*)carve((size_t)NEDGE * 4);
    int* csum_d = (int*)carve(64 * 4);
    int* csum_s = (int*)carve(64 * 4);
    int* csx_d  = (int*)carve(64 * 4);
    int* csx_s  = (int*)carve(64 * 4);
    u16* WlT   = (u16*)carve((size_t)NLAY * 2 * HDIM * HDIM * 2);
    u16* WrT   = (u16*)carve((size_t)NLAY * 2 * HDIM * HDIM * 2);
    u16* agg_d = (u16*)carve((size_t)NDEV * HDIM * 2);
    u16* agg_s = (u16*)carve((size_t)NSRV * HDIM * 2);
    u16* xb_s  = (u16*)carve((size_t)NSRV * 64 * 2);
    u16* xb_d  = (u16*)carve((size_t)NDEV * 32 * 2);
    u16* WTp_s = (u16*)carve((size_t)HDIM * 64 * 2);
    u16* WTp_d = (u16*)carve((size_t)HDIM * 32 * 2);

    hipMemsetAsync(cnt_d, 0, (size_t)NDEV * 4, stream);
    hipMemsetAsync(cnt_s, 0, (size_t)NSRV * 4, stream);

    cast_bf16<<<(NSRV * 64 / 2 + 255) / 256, 256, 0, stream>>>(x_s, xb_s, NSRV * 64 / 2);
    cast_bf16<<<(NDEV * 32 / 2 + 255) / 256, 256, 0, stream>>>(x_d, xb_d, NDEV * 32 / 2);
    transpose_wp<64><<<dim3(16, 2), dim3(32, 8), 0, stream>>>(W_srv, WTp_s);
    transpose_wp<32><<<dim3(16, 1), dim3(32, 8), 0, stream>>>(W_dev, WTp_d);
    transpose_w<<<dim3(16, 16, 16), dim3(32, 8), 0, stream>>>(Wl, Wr, WlT, WrT);

    proj_gemm<64><<<dim3((NSRV + 127) / 128, 4), 256, 0, stream>>>(xb_s, WTp_s, b_srv, hA_s, NSRV);
    proj_gemm<32><<<dim3((NDEV + 127) / 128, 4), 256, 0, stream>>>(xb_d, WTp_d, b_dev, hA_d, NDEV);

    count_k<<<(2 * NEDGE + 255) / 256, 256, 0, stream>>>(e_sd_dst, e_ds_dst, cnt_d, cnt_s);
    scan_a_both<<<NCH_D + NCH_S, 256, 0, stream>>>(cnt_d, off_d, csum_d, cnt_s, off_s, csum_s);
    scan_k<<<2, 64, 0, stream>>>(csum_d, csx_d, csx_d, NCH_D, csum_s, csx_s, csx_s, NCH_S);
    scan_c_both<<<(NDEV + NSRV + 255) / 256, 256, 0, stream>>>(off_d, cur_d, csx_d, off_s, cur_s, csx_s);
    fill_k<<<(2 * NEDGE + 255) / 256, 256, 0, stream>>>(e_sd_src, e_sd_dst, cur_d, src_d,
                                                        e_ds_src, e_ds_dst, cur_s, src_s);

    const int MB_D = (NDEV + 255) / 256;       // 196
    const int MB_S = (NSRV + 255) / 256;       // 40
    const int GD = ((MB_D + 7) / 8) * 32;      // 800
    const int GS = ((MB_S + 7) / 8) * 32;      // 160

    for (int l = 0; l < NLAY; ++l) {
        const u16* hs_in = (l & 1) ? hB_s : hA_s;
        const u16* hd_in = (l & 1) ? hB_d : hA_d;
        u16* hs_out = (l & 1) ? hA_s : hB_s;
        u16* hd_out = (l & 1) ? hA_d : hB_d;

        const u16* WlT0 = WlT + (size_t)(l * 2 + 0) * HDIM * HDIM;
        const u16* WrT0 = WrT + (size_t)(l * 2 + 0) * HDIM * HDIM;
        const u16* WlT1 = WlT + (size_t)(l * 2 + 1) * HDIM * HDIM;
        const u16* WrT1 = WrT + (size_t)(l * 2 + 1) * HDIM * HDIM;
        const float* bl0 = bl + (size_t)(l * 2 + 0) * HDIM;
        const float* bl1 = bl + (size_t)(l * 2 + 1) * HDIM;

        aggregate_both<<<(NDEV + NSRV + 3) / 4, 256, 0, stream>>>(
            hs_in, hd_in, off_d, cnt_d, src_d, off_s, cnt_s, src_s, agg_d, agg_s);
        gemm_both<<<GD + GS, 512, 0, stream>>>(
            agg_d, hd_in, WlT0, WrT0, bl0, hd_out, NDEV, MB_D, GD,
            agg_s, hs_in, WlT1, WrT1, bl1, hs_out, NSRV, MB_S);
    }

    int hi = (int)NTOT;
    while (hi > 4000 && (hi % 2 == 0)) {
        int lo = hi / 2;
        int nblk = (hi - lo + 255) / 256;
        expand_k<<<nblk, 256, 0, stream>>>(fout, lo, hi);
        hi = lo;
    }
    expand_final<<<1, 512, 0, stream>>>(fout, hi);
}

// Round 15
// 992.118 us; speedup vs baseline: 1.4294x; 1.4294x over previous
//
#include <hip/hip_runtime.h>
#include <cstdint>

#define NSRV 10000
#define NDEV 50000
#define HDIM 512
#define NEDGE 300000
#define NLAY 4
#define SCHUNK 2048
#define NCH_D ((NDEV + SCHUNK - 1) / SCHUNK)  // 25
#define NCH_S ((NSRV + SCHUNK - 1) / SCHUNK)  // 5

typedef unsigned int u32;
typedef unsigned short u16;

typedef __bf16 bf16x8 __attribute__((ext_vector_type(8)));
typedef float f32x4 __attribute__((ext_vector_type(4)));

// ---------- bf16 helpers ----------
__device__ __forceinline__ float bflo(u32 u) { return __uint_as_float(u << 16); }
__device__ __forceinline__ float bfhi(u32 u) { return __uint_as_float(u & 0xffff0000u); }
__device__ __forceinline__ float bf2f(u16 v) { return __uint_as_float((u32)v << 16); }
__device__ __forceinline__ u16 f2bf(float f) {
    u32 u = __float_as_uint(f);
    u += 0x7fffu + ((u >> 16) & 1u);  // RNE
    return (u16)(u >> 16);
}
__device__ __forceinline__ u32 pack2(float a, float b) {
    return (u32)f2bf(a) | ((u32)f2bf(b) << 16);
}

// ---------- f32 -> bf16 cast ----------
__global__ void cast_bf16(const float* __restrict__ src, u16* __restrict__ dst, int n2) {
    int i = blockIdx.x * 256 + threadIdx.x;
    if (i < n2) {
        float2 v = *(const float2*)(src + 2 * (size_t)i);
        *(u32*)(dst + 2 * (size_t)i) = pack2(v.x, v.y);
    }
}

// ---------- weight transpose + bf16 cast (512x512 x16 matrices) ----------
__global__ void transpose_w(const float* __restrict__ Wl, const float* __restrict__ Wr,
                            u16* __restrict__ WlT, u16* __restrict__ WrT) {
    __shared__ float t[32][33];
    int z = blockIdx.z;
    const float* Wsrc = ((z < 8) ? Wl : Wr) + (size_t)(z & 7) * HDIM * HDIM;
    u16* Wdst = ((z < 8) ? WlT : WrT) + (size_t)(z & 7) * HDIM * HDIM;
    int n0 = blockIdx.x * 32, k0 = blockIdx.y * 32;
    int x = threadIdx.x, y = threadIdx.y;
#pragma unroll
    for (int i = 0; i < 4; ++i)
        t[y + 8 * i][x] = Wsrc[(size_t)(k0 + y + 8 * i) * HDIM + n0 + x];
    __syncthreads();
    if (x < 16) {
#pragma unroll
        for (int i = 0; i < 4; ++i) {
            int n = n0 + y + 8 * i;
            u32 v = pack2(t[2 * x][y + 8 * i], t[2 * x + 1][y + 8 * i]);
            *(u32*)(Wdst + (size_t)n * HDIM + k0 + 2 * x) = v;
        }
    }
}

// ---------- proj weight transpose: W[K][512] f32 -> WT[512][K] bf16 ----------
template <int K>
__global__ void transpose_wp(const float* __restrict__ W, u16* __restrict__ WT) {
    __shared__ float t[32][33];
    int n0 = blockIdx.x * 32, k0 = blockIdx.y * 32;
    int x = threadIdx.x, y = threadIdx.y;
#pragma unroll
    for (int i = 0; i < 4; ++i)
        t[y + 8 * i][x] = W[(size_t)(k0 + y + 8 * i) * HDIM + n0 + x];
    __syncthreads();
    if (x < 16) {
#pragma unroll
        for (int i = 0; i < 4; ++i) {
            int n = n0 + y + 8 * i;
            u32 v = pack2(t[2 * x][y + 8 * i], t[2 * x + 1][y + 8 * i]);
            *(u32*)(WT + (size_t)n * K + k0 + 2 * x) = v;
        }
    }
}

// ---------- MFMA projection ----------
template <int KTOT>
__launch_bounds__(256, 2)
__global__ void proj_gemm(const u16* __restrict__ A, const u16* __restrict__ B,
                          const float* __restrict__ bias, u16* __restrict__ C, int M) {
    constexpr int NKC = KTOT / 8;
    __shared__ __align__(16) u16 As[NKC][128][8];
    __shared__ __align__(16) u16 Bs[NKC][128][8];
    const int tid = threadIdx.x;
    const int lane = tid & 63;
    const int w = tid >> 6;
    const int m0 = blockIdx.x * 128, n0 = blockIdx.y * 128;
    const int wm = w >> 1, wn = w & 1;
    const int g = lane >> 4, r = lane & 15;

    for (int idx = tid; idx < NKC * 128; idx += 256) {
        int row = idx / NKC, kc = idx % NKC;
        int ra = m0 + row; if (ra > M - 1) ra = M - 1;
        *(uint4*)&As[kc][row][0] = *(const uint4*)(A + (size_t)ra * KTOT + kc * 8);
        *(uint4*)&Bs[kc][row][0] = *(const uint4*)(B + (size_t)(n0 + row) * KTOT + kc * 8);
    }
    __syncthreads();

    f32x4 acc[4][4];
#pragma unroll
    for (int i = 0; i < 4; ++i)
#pragma unroll
        for (int j = 0; j < 4; ++j) acc[i][j] = (f32x4){0.f, 0.f, 0.f, 0.f};

#pragma unroll
    for (int t = 0; t < KTOT / 32; ++t) {
        bf16x8 af[4], bfr[4];
#pragma unroll
        for (int i = 0; i < 4; ++i) {
            af[i]  = *(const bf16x8*)&As[t * 4 + g][wm * 64 + i * 16 + r][0];
            bfr[i] = *(const bf16x8*)&Bs[t * 4 + g][wn * 64 + i * 16 + r][0];
        }
#pragma unroll
        for (int i = 0; i < 4; ++i)
#pragma unroll
            for (int j = 0; j < 4; ++j)
                acc[i][j] = __builtin_amdgcn_mfma_f32_16x16x32_bf16(af[i], bfr[j], acc[i][j], 0, 0, 0);
    }
    __syncthreads();

    float bv[4];
#pragma unroll
    for (int j = 0; j < 4; ++j) bv[j] = bias[n0 + wn * 64 + j * 16 + r];

    u16* ep = ((u16*)As) + w * 1024;
    const int rr = lane >> 3;
    const int cc = (lane & 7) * 8;
#pragma unroll
    for (int i = 0; i < 4; ++i) {
#pragma unroll
        for (int j = 0; j < 4; ++j)
#pragma unroll
            for (int q = 0; q < 4; ++q)
                ep[(g * 4 + q) * 64 + j * 16 + r] = f2bf(acc[i][j][q] + bv[j]);
        __syncthreads();
        int row0 = m0 + wm * 64 + i * 16 + rr;
        int row1 = row0 + 8;
        uint4 v0 = *(uint4*)&ep[rr * 64 + cc];
        uint4 v1 = *(uint4*)&ep[(rr + 8) * 64 + cc];
        if (row0 < M) *(uint4*)(C + (size_t)row0 * HDIM + n0 + wn * 64 + cc) = v0;
        if (row1 < M) *(uint4*)(C + (size_t)row1 * HDIM + n0 + wn * 64 + cc) = v1;
        __syncthreads();
    }
}

// ---------- CSR build ----------
__global__ void count_k(const int* __restrict__ d_sd, const int* __restrict__ d_ds,
                        int* __restrict__ cd, int* __restrict__ cs) {
    int i = blockIdx.x * 256 + threadIdx.x;
    if (i < NEDGE) atomicAdd(&cd[d_sd[i]], 1);
    else if (i < 2 * NEDGE) atomicAdd(&cs[d_ds[i - NEDGE]], 1);
}

__global__ void scan_a_both(const int* __restrict__ cd, int* __restrict__ od, int* __restrict__ csd,
                            const int* __restrict__ cs, int* __restrict__ os, int* __restrict__ css) {
    __shared__ int wsum[4];
    int blk = blockIdx.x;
    const int* c; int* o; int* csum; int n; int cb;
    if (blk < NCH_D) { c = cd; o = od; csum = csd; n = NDEV; cb = blk; }
    else             { c = cs; o = os; csum = css; n = NSRV; cb = blk - NCH_D; }
    int tid = threadIdx.x;
    int base = cb * SCHUNK;
    int idx0 = base + tid * 8;
    int v[8];
    int s = 0;
#pragma unroll
    for (int i = 0; i < 8; ++i) {
        int idx = idx0 + i;
        v[i] = (idx < n) ? c[idx] : 0;
        s += v[i];
    }
    int lane = tid & 63, wv = tid >> 6;
    int ss = s;
#pragma unroll
    for (int off = 1; off < 64; off <<= 1) {
        int t = __shfl_up(ss, off);
        if (lane >= off) ss += t;
    }
    if (lane == 63) wsum[wv] = ss;
    __syncthreads();
    int woff = 0;
#pragma unroll
    for (int i = 0; i < 4; ++i)
        if (i < wv) woff += wsum[i];
    int ex = woff + ss - s;
#pragma unroll
    for (int i = 0; i < 8; ++i) {
        int idx = idx0 + i;
        if (idx < n) o[idx] = ex;
        ex += v[i];
    }
    if (tid == 255) csum[cb] = woff + ss;
}

__global__ void scan_k(const int* __restrict__ cA, int* __restrict__ oA, int* __restrict__ uA, int nA,
                       const int* __restrict__ cB, int* __restrict__ oB, int* __restrict__ uB, int nB) {
    const int* c; int* o; int* u; int n;
    if (blockIdx.x == 0) { c = cA; o = oA; u = uA; n = nA; }
    else                 { c = cB; o = oB; u = uB; n = nB; }
    int lane = threadIdx.x;
    int carry = 0;
    for (int base = 0; base < n; base += 64) {
        int idx = base + lane;
        int v = (idx < n) ? c[idx] : 0;
        int s = v;
#pragma unroll
        for (int off = 1; off < 64; off <<= 1) {
            int t = __shfl_up(s, off);
            if (lane >= off) s += t;
        }
        if (idx < n) { int ex = carry + s - v; o[idx] = ex; u[idx] = ex; }
        carry += __shfl(s, 63);
    }
}

__global__ void scan_c_both(int* __restrict__ od, int* __restrict__ curd, const int* __restrict__ csxd,
                            int* __restrict__ os, int* __restrict__ curs, const int* __restrict__ csxs) {
    int i = blockIdx.x * 256 + threadIdx.x;
    if (i < NDEV) {
        int v = od[i] + csxd[i / SCHUNK];
        od[i] = v;
        curd[i] = v;
    } else if (i < NDEV + NSRV) {
        int j = i - NDEV;
        int v = os[j] + csxs[j / SCHUNK];
        os[j] = v;
        curs[j] = v;
    }
}

__global__ void fill_k(const int* __restrict__ s_sd, const int* __restrict__ d_sd,
                       int* __restrict__ cur_d, int* __restrict__ srcs_d,
                       const int* __restrict__ s_ds, const int* __restrict__ d_ds,
                       int* __restrict__ cur_s, int* __restrict__ srcs_s) {
    int i = blockIdx.x * 256 + threadIdx.x;
    if (i < NEDGE) {
        int p = atomicAdd(&cur_d[d_sd[i]], 1);
        srcs_d[p] = s_sd[i];
    } else if (i < 2 * NEDGE) {
        int j = i - NEDGE;
        int p = atomicAdd(&cur_s[d_ds[j]], 1);
        srcs_s[p] = s_ds[j];
    }
}

// ---------- fused scatter-mean, 8-wide MLP ----------
__global__ void aggregate_both(const u16* __restrict__ hs, const u16* __restrict__ hd,
                               const int* __restrict__ offs_d, const int* __restrict__ cnt_d,
                               const int* __restrict__ src_d,
                               const int* __restrict__ offs_s, const int* __restrict__ cnt_s,
                               const int* __restrict__ src_s,
                               u16* __restrict__ agg_d, u16* __restrict__ agg_s) {
    int wv = threadIdx.x >> 6, lane = threadIdx.x & 63;
    int d = blockIdx.x * 4 + wv;
    const u16* h; const int* offs; const int* cnt; const int* srcs; u16* agg; int idx;
    if (d < NDEV)              { h = hs; offs = offs_d; cnt = cnt_d; srcs = src_d; agg = agg_d; idx = d; }
    else if (d < NDEV + NSRV)  { h = hd; offs = offs_s; cnt = cnt_s; srcs = src_s; agg = agg_s; idx = d - NDEV; }
    else return;
    int beg = offs[idx], deg = cnt[idx];
    float acc[8] = {0.f, 0.f, 0.f, 0.f, 0.f, 0.f, 0.f, 0.f};
    const size_t lanecol = (size_t)lane * 8;
    auto accum = [&](const uint4& q) {
        acc[0] += bflo(q.x); acc[1] += bfhi(q.x);
        acc[2] += bflo(q.y); acc[3] += bfhi(q.y);
        acc[4] += bflo(q.z); acc[5] += bfhi(q.z);
        acc[6] += bflo(q.w); acc[7] += bfhi(q.w);
    };
    for (int t0 = 0; t0 < deg; t0 += 64) {
        int nch = min(64, deg - t0);
        int sv = (t0 + lane < deg) ? srcs[beg + t0 + lane] : 0;
        int j = 0;
        for (; j + 8 <= nch; j += 8) {
            uint4 q[8];
#pragma unroll
            for (int u_ = 0; u_ < 8; ++u_) {
                int s = __shfl(sv, j + u_);
                q[u_] = *(const uint4*)(h + (size_t)s * HDIM + lanecol);
            }
#pragma unroll
            for (int u_ = 0; u_ < 8; ++u_) accum(q[u_]);
        }
        for (; j + 4 <= nch; j += 4) {
            uint4 q[4];
#pragma unroll
            for (int u_ = 0; u_ < 4; ++u_) {
                int s = __shfl(sv, j + u_);
                q[u_] = *(const uint4*)(h + (size_t)s * HDIM + lanecol);
            }
#pragma unroll
            for (int u_ = 0; u_ < 4; ++u_) accum(q[u_]);
        }
        for (; j < nch; ++j) {
            int s = __shfl(sv, j);
            const uint4 q = *(const uint4*)(h + (size_t)s * HDIM + lanecol);
            accum(q);
        }
    }
    float sc = 1.f / (float)(deg > 0 ? deg : 1);
    uint4 o;
    o.x = pack2(acc[0] * sc, acc[1] * sc);
    o.y = pack2(acc[2] * sc, acc[3] * sc);
    o.z = pack2(acc[4] * sc, acc[5] * sc);
    o.w = pack2(acc[6] * sc, acc[7] * sc);
    *(uint4*)(agg + (size_t)idx * HDIM + lanecol) = o;
}

// ---------- fused SAGE GEMM 256x128, 2-deep prefetch with NAMED register sets ----------
// setA holds even tiles (-> buf0), setB holds odd tiles (-> buf1). K-loop unrolled
// by 2 so every register access is compile-time-static (no scratch spill, rule #20).
// Each gload's swrite is a full iteration later -> vmcnt wait covered by compute.
__launch_bounds__(512, 2)
__global__ void gemm_both(const u16* __restrict__ A1d, const u16* __restrict__ A2d,
                          const u16* __restrict__ B1d, const u16* __restrict__ B2d,
                          const float* __restrict__ bd, u16* __restrict__ Cd, int Md, int MBd, int GD,
                          const u16* __restrict__ A1s, const u16* __restrict__ A2s,
                          const u16* __restrict__ B1s, const u16* __restrict__ B2s,
                          const float* __restrict__ bs, u16* __restrict__ Cs, int Ms, int MBs) {
    int b = blockIdx.x;
    const u16 *A1, *A2, *B1, *B2; const float* bias; u16* C; int M, MB;
    if (b < GD) { A1 = A1d; A2 = A2d; B1 = B1d; B2 = B2d; bias = bd; C = Cd; M = Md; MB = MBd; }
    else { b -= GD; A1 = A1s; A2 = A2s; B1 = B1s; B2 = B2s; bias = bs; C = Cs; M = Ms; MB = MBs; }
    const int mi = (b >> 5) * 8 + (b & 7);
    const int ni = (b >> 3) & 3;
    if (mi >= MB) return;

    __shared__ __align__(16) u16 As[2][4][256][8];  // 32 KB
    __shared__ __align__(16) u16 Bs[2][4][128][8];  // 16 KB
    const int tid = threadIdx.x;
    const int lane = tid & 63;
    const int w = tid >> 6;
    const int m0 = mi * 256, n0 = ni * 128;
    const int wm = w >> 1, wn = w & 1;
    const int g = lane >> 4, r = lane & 15;

    const int srow = tid >> 2;          // 0..127
    const int skc  = tid & 3;           // 0..3

    f32x4 acc[4][4];
#pragma unroll
    for (int i = 0; i < 4; ++i)
#pragma unroll
        for (int j = 0; j < 4; ++j) acc[i][j] = (f32x4){0.f, 0.f, 0.f, 0.f};

    // clamped row addresses (loop-invariant)
    int r0c = m0 + srow;       if (r0c > M - 1) r0c = M - 1;
    int r1c = m0 + srow + 128; if (r1c > M - 1) r1c = M - 1;
    const int nr = n0 + srow;

    uint4 a0A, a1A, b0A;  // even tiles
    uint4 a0B, a1B, b0B;  // odd tiles
    auto gloadA = [&](int kt) {
        const u16* Ap = (kt < 16) ? A1 : A2;
        const u16* Bp = (kt < 16) ? B1 : B2;
        const int kb = (kt & 15) * 32 + skc * 8;
        a0A = *(const uint4*)(Ap + (size_t)r0c * HDIM + kb);
        a1A = *(const uint4*)(Ap + (size_t)r1c * HDIM + kb);
        b0A = *(const uint4*)(Bp + (size_t)nr * HDIM + kb);
    };
    auto gloadB = [&](int kt) {
        const u16* Ap = (kt < 16) ? A1 : A2;
        const u16* Bp = (kt < 16) ? B1 : B2;
        const int kb = (kt & 15) * 32 + skc * 8;
        a0B = *(const uint4*)(Ap + (size_t)r0c * HDIM + kb);
        a1B = *(const uint4*)(Ap + (size_t)r1c * HDIM + kb);
        b0B = *(const uint4*)(Bp + (size_t)nr * HDIM + kb);
    };
    auto swriteA = [&]() {  // even tile -> buf0
        *(uint4*)&As[0][skc][srow][0]       = a0A;
        *(uint4*)&As[0][skc][srow + 128][0] = a1A;
        *(uint4*)&Bs[0][skc][srow][0]       = b0A;
    };
    auto swriteB = [&]() {  // odd tile -> buf1
        *(uint4*)&As[1][skc][srow][0]       = a0B;
        *(uint4*)&As[1][skc][srow + 128][0] = a1B;
        *(uint4*)&Bs[1][skc][srow][0]       = b0B;
    };
    auto compute = [&](int buf) {
        bf16x8 af[4], bfr[4];
#pragma unroll
        for (int i = 0; i < 4; ++i) {
            af[i]  = *(const bf16x8*)&As[buf][g][wm * 64 + i * 16 + r][0];
            bfr[i] = *(const bf16x8*)&Bs[buf][g][wn * 64 + i * 16 + r][0];
        }
#pragma unroll
        for (int i = 0; i < 4; ++i)
#pragma unroll
            for (int j = 0; j < 4; ++j)
                acc[i][j] = __builtin_amdgcn_mfma_f32_16x16x32_bf16(af[i], bfr[j], acc[i][j], 0, 0, 0);
    };

    // prologue: tile0 -> setA -> buf0; tile1 -> setB (written in first even phase)
    gloadA(0);
    swriteA();
    gloadB(1);
    __syncthreads();
    for (int kt = 0; kt < 32; kt += 2) {
        // even phase: compute tile kt from buf0
        if (kt + 2 < 32) gloadA(kt + 2);   // -> setA (consumed)
        swriteB();                          // tile kt+1 -> buf1 (loads 1 iter old)
        compute(0);
        __syncthreads();
        // odd phase: compute tile kt+1 from buf1
        if (kt + 3 < 32) gloadB(kt + 3);   // -> setB (consumed)
        if (kt + 2 < 32) swriteA();        // tile kt+2 -> buf0 (loads 1 iter old)
        compute(1);
        __syncthreads();
    }

    // epilogue: 2 i-blocks per LDS staging round
    float bv[4];
#pragma unroll
    for (int j = 0; j < 4; ++j) bv[j] = bias[n0 + wn * 64 + j * 16 + r];

    u16* ep = ((u16*)As) + w * 2048;
    const int rr = lane >> 3;
    const int cc = (lane & 7) * 8;
#pragma unroll
    for (int ih = 0; ih < 2; ++ih) {
#pragma unroll
        for (int ii = 0; ii < 2; ++ii) {
            int i = ih * 2 + ii;
#pragma unroll
            for (int j = 0; j < 4; ++j)
#pragma unroll
                for (int q = 0; q < 4; ++q)
                    ep[ii * 1024 + (g * 4 + q) * 64 + j * 16 + r] =
                        f2bf(fmaxf(acc[i][j][q] + bv[j], 0.f));
        }
        __syncthreads();
#pragma unroll
        for (int ii = 0; ii < 2; ++ii) {
            int i = ih * 2 + ii;
            int row0 = m0 + wm * 64 + i * 16 + rr;
            int row1 = row0 + 8;
            uint4 v0 = *(uint4*)&ep[ii * 1024 + rr * 64 + cc];
            uint4 v1 = *(uint4*)&ep[ii * 1024 + (rr + 8) * 64 + cc];
            if (row0 < M) *(uint4*)(C + (size_t)row0 * HDIM + n0 + wn * 64 + cc) = v0;
            if (row1 < M) *(uint4*)(C + (size_t)row1 * HDIM + n0 + wn * 64 + cc) = v1;
        }
        __syncthreads();
    }
}

// ---------- in-place bf16 -> f32 widening of d_out ----------
__global__ void expand_k(float* out, int lo, int hi) {
    const u16* src = (const u16*)out;
    int j = lo + blockIdx.x * 256 + threadIdx.x;
    if (j < hi) {
        float v = bf2f(src[j]);
        out[(size_t)j] = v;
    }
}
__global__ void expand_final(float* out, int n) {
    __shared__ u16 tmp[4096];
    const u16* src = (const u16*)out;
    int tid = threadIdx.x;
    for (int i = tid; i < n; i += blockDim.x) tmp[i] = src[i];
    __syncthreads();
    for (int i = tid; i < n; i += blockDim.x) out[(size_t)i] = bf2f(tmp[i]);
}

// ---------- host orchestration ----------
extern "C" void kernel_launch(void* const* d_in, const int* in_sizes, int n_in,
                              void* d_out, int out_size, void* d_ws, size_t ws_size,
                              hipStream_t stream) {
    const float* x_s   = (const float*)d_in[0];
    const float* x_d   = (const float*)d_in[1];
    const float* W_srv = (const float*)d_in[2];
    const float* b_srv = (const float*)d_in[3];
    const float* W_dev = (const float*)d_in[4];
    const float* b_dev = (const float*)d_in[5];
    const float* Wl    = (const float*)d_in[6];
    const float* bl    = (const float*)d_in[7];
    const float* Wr    = (const float*)d_in[8];
    const int* e_sd_src = (const int*)d_in[9];
    const int* e_sd_dst = (const int*)d_in[10];
    const int* e_ds_src = (const int*)d_in[11];
    const int* e_ds_dst = (const int*)d_in[12];

    const size_t NTOT = (size_t)(NSRV + NDEV) * HDIM;
    float* fout = (float*)d_out;
    u16* u = (u16*)d_out;
    u16* hA_s = u;
    u16* hA_d = u + (size_t)NSRV * HDIM;
    u16* hB_s = u + NTOT;
    u16* hB_d = u + NTOT + (size_t)NSRV * HDIM;

    char* p = (char*)d_ws;
    auto carve = [&](size_t bytes) -> void* {
        void* ret = (void*)p;
        p += (bytes + 255) & ~(size_t)255;
        return ret;
    };
    int* cnt_d = (int*)carve((size_t)NDEV * 4);
    int* cnt_s = (int*)carve((size_t)NSRV * 4);
    int* off_d = (int*)carve((size_t)NDEV * 4);
    int* off_s = (int*)carve((size_t)NSRV * 4);
    int* cur_d = (int*)carve((size_t)NDEV * 4);
    int* cur_s = (int*)carve((size_t)NSRV * 4);
    int* src_d = (int*)carve((size_t)NEDGE * 4);
    int* src_s = (int*)carve((size_t)NEDGE * 4);
    int* csum_d = (int*)carve(64 * 4);
    int* csum_s = (int*)carve(64 * 4);
    int* csx_d  = (int*)carve(64 * 4);
    int* csx_s  = (int*)carve(64 * 4);
    u16* WlT   = (u16*)carve((size_t)NLAY * 2 * HDIM * HDIM * 2);
    u16* WrT   = (u16*)carve((size_t)NLAY * 2 * HDIM * HDIM * 2);
    u16* agg_d = (u16*)carve((size_t)NDEV * HDIM * 2);
    u16* agg_s = (u16*)carve((size_t)NSRV * HDIM * 2);
    u16* xb_s  = (u16*)carve((size_t)NSRV * 64 * 2);
    u16* xb_d  = (u16*)carve((size_t)NDEV * 32 * 2);
    u16* WTp_s = (u16*)carve((size_t)HDIM * 64 * 2);
    u16* WTp_d = (u16*)carve((size_t)HDIM * 32 * 2);

    hipMemsetAsync(cnt_d, 0, (size_t)NDEV * 4, stream);
    hipMemsetAsync(cnt_s, 0, (size_t)NSRV * 4, stream);

    cast_bf16<<<(NSRV * 64 / 2 + 255) / 256, 256, 0, stream>>>(x_s, xb_s, NSRV * 64 / 2);
    cast_bf16<<<(NDEV * 32 / 2 + 255) / 256, 256, 0, stream>>>(x_d, xb_d, NDEV * 32 / 2);
    transpose_wp<64><<<dim3(16, 2), dim3(32, 8), 0, stream>>>(W_srv, WTp_s);
    transpose_wp<32><<<dim3(16, 1), dim3(32, 8), 0, stream>>>(W_dev, WTp_d);
    transpose_w<<<dim3(16, 16, 16), dim3(32, 8), 0, stream>>>(Wl, Wr, WlT, WrT);

    proj_gemm<64><<<dim3((NSRV + 127) / 128, 4), 256, 0, stream>>>(xb_s, WTp_s, b_srv, hA_s, NSRV);
    proj_gemm<32><<<dim3((NDEV + 127) / 128, 4), 256, 0, stream>>>(xb_d, WTp_d, b_dev, hA_d, NDEV);

    count_k<<<(2 * NEDGE + 255) / 256, 256, 0, stream>>>(e_sd_dst, e_ds_dst, cnt_d, cnt_s);
    scan_a_both<<<NCH_D + NCH_S, 256, 0, stream>>>(cnt_d, off_d, csum_d, cnt_s, off_s, csum_s);
    scan_k<<<2, 64, 0, stream>>>(csum_d, csx_d, csx_d, NCH_D, csum_s, csx_s, csx_s, NCH_S);
    scan_c_both<<<(NDEV + NSRV + 255) / 256, 256, 0, stream>>>(off_d, cur_d, csx_d, off_s, cur_s, csx_s);
    fill_k<<<(2 * NEDGE + 255) / 256, 256, 0, stream>>>(e_sd_src, e_sd_dst, cur_d, src_d,
                                                        e_ds_src, e_ds_dst, cur_s, src_s);

    const int MB_D = (NDEV + 255) / 256;       // 196
    const int MB_S = (NSRV + 255) / 256;       // 40
    const int GD = ((MB_D + 7) / 8) * 32;      // 800
    const int GS = ((MB_S + 7) / 8) * 32;      // 160

    for (int l = 0; l < NLAY; ++l) {
        const u16* hs_in = (l & 1) ? hB_s : hA_s;
        const u16* hd_in = (l & 1) ? hB_d : hA_d;
        u16* hs_out = (l & 1) ? hA_s : hB_s;
        u16* hd_out = (l & 1) ? hA_d : hB_d;

        const u16* WlT0 = WlT + (size_t)(l * 2 + 0) * HDIM * HDIM;
        const u16* WrT0 = WrT + (size_t)(l * 2 + 0) * HDIM * HDIM;
        const u16* WlT1 = WlT + (size_t)(l * 2 + 1) * HDIM * HDIM;
        const u16* WrT1 = WrT + (size_t)(l * 2 + 1) * HDIM * HDIM;
        const float* bl0 = bl + (size_t)(l * 2 + 0) * HDIM;
        const float* bl1 = bl + (size_t)(l * 2 + 1) * HDIM;

        aggregate_both<<<(NDEV + NSRV + 3) / 4, 256, 0, stream>>>(
            hs_in, hd_in, off_d, cnt_d, src_d, off_s, cnt_s, src_s, agg_d, agg_s);
        gemm_both<<<GD + GS, 512, 0, stream>>>(
            agg_d, hd_in, WlT0, WrT0, bl0, hd_out, NDEV, MB_D, GD,
            agg_s, hs_in, WlT1, WrT1, bl1, hs_out, NSRV, MB_S);
    }

    int hi = (int)NTOT;
    while (hi > 4000 && (hi % 2 == 0)) {
        int lo = hi / 2;
        int nblk = (hi - lo + 255) / 256;
        expand_k<<<nblk, 256, 0, stream>>>(fout, lo, hi);
        hi = lo;
    }
    expand_final<<<1, 512, 0, stream>>>(fout, hi);
}

// Round 16
// 857.058 us; speedup vs baseline: 1.6547x; 1.1576x over previous
//
#include <hip/hip_runtime.h>
#include <cstdint>

#define NSRV 10000
#define NDEV 50000
#define HDIM 512
#define NEDGE 300000
#define NLAY 4
#define SCHUNK 2048
#define NCH_D ((NDEV + SCHUNK - 1) / SCHUNK)  // 25
#define NCH_S ((NSRV + SCHUNK - 1) / SCHUNK)  // 5

typedef unsigned int u32;
typedef unsigned short u16;

typedef __bf16 bf16x8 __attribute__((ext_vector_type(8)));
typedef float f32x4 __attribute__((ext_vector_type(4)));

// ---------- bf16 helpers ----------
__device__ __forceinline__ float bflo(u32 u) { return __uint_as_float(u << 16); }
__device__ __forceinline__ float bfhi(u32 u) { return __uint_as_float(u & 0xffff0000u); }
__device__ __forceinline__ float bf2f(u16 v) { return __uint_as_float((u32)v << 16); }
__device__ __forceinline__ u16 f2bf(float f) {
    u32 u = __float_as_uint(f);
    u += 0x7fffu + ((u >> 16) & 1u);  // RNE
    return (u16)(u >> 16);
}
__device__ __forceinline__ u32 pack2(float a, float b) {
    return (u32)f2bf(a) | ((u32)f2bf(b) << 16);
}

// ---------- f32 -> bf16 cast ----------
__global__ void cast_bf16(const float* __restrict__ src, u16* __restrict__ dst, int n2) {
    int i = blockIdx.x * 256 + threadIdx.x;
    if (i < n2) {
        float2 v = *(const float2*)(src + 2 * (size_t)i);
        *(u32*)(dst + 2 * (size_t)i) = pack2(v.x, v.y);
    }
}

// ---------- weight transpose + bf16 cast (512x512 x16 matrices) ----------
__global__ void transpose_w(const float* __restrict__ Wl, const float* __restrict__ Wr,
                            u16* __restrict__ WlT, u16* __restrict__ WrT) {
    __shared__ float t[32][33];
    int z = blockIdx.z;
    const float* Wsrc = ((z < 8) ? Wl : Wr) + (size_t)(z & 7) * HDIM * HDIM;
    u16* Wdst = ((z < 8) ? WlT : WrT) + (size_t)(z & 7) * HDIM * HDIM;
    int n0 = blockIdx.x * 32, k0 = blockIdx.y * 32;
    int x = threadIdx.x, y = threadIdx.y;
#pragma unroll
    for (int i = 0; i < 4; ++i)
        t[y + 8 * i][x] = Wsrc[(size_t)(k0 + y + 8 * i) * HDIM + n0 + x];
    __syncthreads();
    if (x < 16) {
#pragma unroll
        for (int i = 0; i < 4; ++i) {
            int n = n0 + y + 8 * i;
            u32 v = pack2(t[2 * x][y + 8 * i], t[2 * x + 1][y + 8 * i]);
            *(u32*)(Wdst + (size_t)n * HDIM + k0 + 2 * x) = v;
        }
    }
}

// ---------- proj weight transpose: W[K][512] f32 -> WT[512][K] bf16 ----------
template <int K>
__global__ void transpose_wp(const float* __restrict__ W, u16* __restrict__ WT) {
    __shared__ float t[32][33];
    int n0 = blockIdx.x * 32, k0 = blockIdx.y * 32;
    int x = threadIdx.x, y = threadIdx.y;
#pragma unroll
    for (int i = 0; i < 4; ++i)
        t[y + 8 * i][x] = W[(size_t)(k0 + y + 8 * i) * HDIM + n0 + x];
    __syncthreads();
    if (x < 16) {
#pragma unroll
        for (int i = 0; i < 4; ++i) {
            int n = n0 + y + 8 * i;
            u32 v = pack2(t[2 * x][y + 8 * i], t[2 * x + 1][y + 8 * i]);
            *(u32*)(WT + (size_t)n * K + k0 + 2 * x) = v;
        }
    }
}

// ---------- MFMA projection ----------
template <int KTOT>
__launch_bounds__(256, 2)
__global__ void proj_gemm(const u16* __restrict__ A, const u16* __restrict__ B,
                          const float* __restrict__ bias, u16* __restrict__ C, int M) {
    constexpr int NKC = KTOT / 8;
    __shared__ __align__(16) u16 As[NKC][128][8];
    __shared__ __align__(16) u16 Bs[NKC][128][8];
    const int tid = threadIdx.x;
    const int lane = tid & 63;
    const int w = tid >> 6;
    const int m0 = blockIdx.x * 128, n0 = blockIdx.y * 128;
    const int wm = w >> 1, wn = w & 1;
    const int g = lane >> 4, r = lane & 15;

    for (int idx = tid; idx < NKC * 128; idx += 256) {
        int row = idx / NKC, kc = idx % NKC;
        int ra = m0 + row; if (ra > M - 1) ra = M - 1;
        *(uint4*)&As[kc][row][0] = *(const uint4*)(A + (size_t)ra * KTOT + kc * 8);
        *(uint4*)&Bs[kc][row][0] = *(const uint4*)(B + (size_t)(n0 + row) * KTOT + kc * 8);
    }
    __syncthreads();

    f32x4 acc[4][4];
#pragma unroll
    for (int i = 0; i < 4; ++i)
#pragma unroll
        for (int j = 0; j < 4; ++j) acc[i][j] = (f32x4){0.f, 0.f, 0.f, 0.f};

#pragma unroll
    for (int t = 0; t < KTOT / 32; ++t) {
        bf16x8 af[4], bfr[4];
#pragma unroll
        for (int i = 0; i < 4; ++i) {
            af[i]  = *(const bf16x8*)&As[t * 4 + g][wm * 64 + i * 16 + r][0];
            bfr[i] = *(const bf16x8*)&Bs[t * 4 + g][wn * 64 + i * 16 + r][0];
        }
#pragma unroll
        for (int i = 0; i < 4; ++i)
#pragma unroll
            for (int j = 0; j < 4; ++j)
                acc[i][j] = __builtin_amdgcn_mfma_f32_16x16x32_bf16(af[i], bfr[j], acc[i][j], 0, 0, 0);
    }
    __syncthreads();

    float bv[4];
#pragma unroll
    for (int j = 0; j < 4; ++j) bv[j] = bias[n0 + wn * 64 + j * 16 + r];

    u16* ep = ((u16*)As) + w * 1024;
    const int rr = lane >> 3;
    const int cc = (lane & 7) * 8;
#pragma unroll
    for (int i = 0; i < 4; ++i) {
#pragma unroll
        for (int j = 0; j < 4; ++j)
#pragma unroll
            for (int q = 0; q < 4; ++q)
                ep[(g * 4 + q) * 64 + j * 16 + r] = f2bf(acc[i][j][q] + bv[j]);
        __syncthreads();
        int row0 = m0 + wm * 64 + i * 16 + rr;
        int row1 = row0 + 8;
        uint4 v0 = *(uint4*)&ep[rr * 64 + cc];
        uint4 v1 = *(uint4*)&ep[(rr + 8) * 64 + cc];
        if (row0 < M) *(uint4*)(C + (size_t)row0 * HDIM + n0 + wn * 64 + cc) = v0;
        if (row1 < M) *(uint4*)(C + (size_t)row1 * HDIM + n0 + wn * 64 + cc) = v1;
        __syncthreads();
    }
}

// ---------- CSR build ----------
__global__ void count_k(const int* __restrict__ d_sd, const int* __restrict__ d_ds,
                        int* __restrict__ cd, int* __restrict__ cs) {
    int i = blockIdx.x * 256 + threadIdx.x;
    if (i < NEDGE) atomicAdd(&cd[d_sd[i]], 1);
    else if (i < 2 * NEDGE) atomicAdd(&cs[d_ds[i - NEDGE]], 1);
}

__global__ void scan_a_both(const int* __restrict__ cd, int* __restrict__ od, int* __restrict__ csd,
                            const int* __restrict__ cs, int* __restrict__ os, int* __restrict__ css) {
    __shared__ int wsum[4];
    int blk = blockIdx.x;
    const int* c; int* o; int* csum; int n; int cb;
    if (blk < NCH_D) { c = cd; o = od; csum = csd; n = NDEV; cb = blk; }
    else             { c = cs; o = os; csum = css; n = NSRV; cb = blk - NCH_D; }
    int tid = threadIdx.x;
    int base = cb * SCHUNK;
    int idx0 = base + tid * 8;
    int v[8];
    int s = 0;
#pragma unroll
    for (int i = 0; i < 8; ++i) {
        int idx = idx0 + i;
        v[i] = (idx < n) ? c[idx] : 0;
        s += v[i];
    }
    int lane = tid & 63, wv = tid >> 6;
    int ss = s;
#pragma unroll
    for (int off = 1; off < 64; off <<= 1) {
        int t = __shfl_up(ss, off);
        if (lane >= off) ss += t;
    }
    if (lane == 63) wsum[wv] = ss;
    __syncthreads();
    int woff = 0;
#pragma unroll
    for (int i = 0; i < 4; ++i)
        if (i < wv) woff += wsum[i];
    int ex = woff + ss - s;
#pragma unroll
    for (int i = 0; i < 8; ++i) {
        int idx = idx0 + i;
        if (idx < n) o[idx] = ex;
        ex += v[i];
    }
    if (tid == 255) csum[cb] = woff + ss;
}

__global__ void scan_k(const int* __restrict__ cA, int* __restrict__ oA, int* __restrict__ uA, int nA,
                       const int* __restrict__ cB, int* __restrict__ oB, int* __restrict__ uB, int nB) {
    const int* c; int* o; int* u; int n;
    if (blockIdx.x == 0) { c = cA; o = oA; u = uA; n = nA; }
    else                 { c = cB; o = oB; u = uB; n = nB; }
    int lane = threadIdx.x;
    int carry = 0;
    for (int base = 0; base < n; base += 64) {
        int idx = base + lane;
        int v = (idx < n) ? c[idx] : 0;
        int s = v;
#pragma unroll
        for (int off = 1; off < 64; off <<= 1) {
            int t = __shfl_up(s, off);
            if (lane >= off) s += t;
        }
        if (idx < n) { int ex = carry + s - v; o[idx] = ex; u[idx] = ex; }
        carry += __shfl(s, 63);
    }
}

__global__ void scan_c_both(int* __restrict__ od, int* __restrict__ curd, const int* __restrict__ csxd,
                            int* __restrict__ os, int* __restrict__ curs, const int* __restrict__ csxs) {
    int i = blockIdx.x * 256 + threadIdx.x;
    if (i < NDEV) {
        int v = od[i] + csxd[i / SCHUNK];
        od[i] = v;
        curd[i] = v;
    } else if (i < NDEV + NSRV) {
        int j = i - NDEV;
        int v = os[j] + csxs[j / SCHUNK];
        os[j] = v;
        curs[j] = v;
    }
}

__global__ void fill_k(const int* __restrict__ s_sd, const int* __restrict__ d_sd,
                       int* __restrict__ cur_d, int* __restrict__ srcs_d,
                       const int* __restrict__ s_ds, const int* __restrict__ d_ds,
                       int* __restrict__ cur_s, int* __restrict__ srcs_s) {
    int i = blockIdx.x * 256 + threadIdx.x;
    if (i < NEDGE) {
        int p = atomicAdd(&cur_d[d_sd[i]], 1);
        srcs_d[p] = s_sd[i];
    } else if (i < 2 * NEDGE) {
        int j = i - NEDGE;
        int p = atomicAdd(&cur_s[d_ds[j]], 1);
        srcs_s[p] = s_ds[j];
    }
}

// ---------- fused scatter-mean, 8-wide MLP ----------
__global__ void aggregate_both(const u16* __restrict__ hs, const u16* __restrict__ hd,
                               const int* __restrict__ offs_d, const int* __restrict__ cnt_d,
                               const int* __restrict__ src_d,
                               const int* __restrict__ offs_s, const int* __restrict__ cnt_s,
                               const int* __restrict__ src_s,
                               u16* __restrict__ agg_d, u16* __restrict__ agg_s) {
    int wv = threadIdx.x >> 6, lane = threadIdx.x & 63;
    int d = blockIdx.x * 4 + wv;
    const u16* h; const int* offs; const int* cnt; const int* srcs; u16* agg; int idx;
    if (d < NDEV)              { h = hs; offs = offs_d; cnt = cnt_d; srcs = src_d; agg = agg_d; idx = d; }
    else if (d < NDEV + NSRV)  { h = hd; offs = offs_s; cnt = cnt_s; srcs = src_s; agg = agg_s; idx = d - NDEV; }
    else return;
    int beg = offs[idx], deg = cnt[idx];
    float acc[8] = {0.f, 0.f, 0.f, 0.f, 0.f, 0.f, 0.f, 0.f};
    const size_t lanecol = (size_t)lane * 8;
    auto accum = [&](const uint4& q) {
        acc[0] += bflo(q.x); acc[1] += bfhi(q.x);
        acc[2] += bflo(q.y); acc[3] += bfhi(q.y);
        acc[4] += bflo(q.z); acc[5] += bfhi(q.z);
        acc[6] += bflo(q.w); acc[7] += bfhi(q.w);
    };
    for (int t0 = 0; t0 < deg; t0 += 64) {
        int nch = min(64, deg - t0);
        int sv = (t0 + lane < deg) ? srcs[beg + t0 + lane] : 0;
        int j = 0;
        for (; j + 8 <= nch; j += 8) {
            uint4 q[8];
#pragma unroll
            for (int u_ = 0; u_ < 8; ++u_) {
                int s = __shfl(sv, j + u_);
                q[u_] = *(const uint4*)(h + (size_t)s * HDIM + lanecol);
            }
#pragma unroll
            for (int u_ = 0; u_ < 8; ++u_) accum(q[u_]);
        }
        for (; j + 4 <= nch; j += 4) {
            uint4 q[4];
#pragma unroll
            for (int u_ = 0; u_ < 4; ++u_) {
                int s = __shfl(sv, j + u_);
                q[u_] = *(const uint4*)(h + (size_t)s * HDIM + lanecol);
            }
#pragma unroll
            for (int u_ = 0; u_ < 4; ++u_) accum(q[u_]);
        }
        for (; j < nch; ++j) {
            int s = __shfl(sv, j);
            const uint4 q = *(const uint4*)(h + (size_t)s * HDIM + lanecol);
            accum(q);
        }
    }
    float sc = 1.f / (float)(deg > 0 ? deg : 1);
    uint4 o;
    o.x = pack2(acc[0] * sc, acc[1] * sc);
    o.y = pack2(acc[2] * sc, acc[3] * sc);
    o.z = pack2(acc[4] * sc, acc[5] * sc);
    o.w = pack2(acc[6] * sc, acc[7] * sc);
    *(uint4*)(agg + (size_t)idx * HDIM + lanecol) = o;
}

// ---------- fused SAGE GEMM 256x128 (round-13 schedule: gload -> compute -> swrite) ----------
// Reg-staged double-buffered LDS; XCD-grouped decode per segment. This simple
// 2-barrier order measured fastest (96us); deeper pipelining regressed (r14/r15).
__launch_bounds__(512, 2)
__global__ void gemm_both(const u16* __restrict__ A1d, const u16* __restrict__ A2d,
                          const u16* __restrict__ B1d, const u16* __restrict__ B2d,
                          const float* __restrict__ bd, u16* __restrict__ Cd, int Md, int MBd, int GD,
                          const u16* __restrict__ A1s, const u16* __restrict__ A2s,
                          const u16* __restrict__ B1s, const u16* __restrict__ B2s,
                          const float* __restrict__ bs, u16* __restrict__ Cs, int Ms, int MBs) {
    int b = blockIdx.x;
    const u16 *A1, *A2, *B1, *B2; const float* bias; u16* C; int M, MB;
    if (b < GD) { A1 = A1d; A2 = A2d; B1 = B1d; B2 = B2d; bias = bd; C = Cd; M = Md; MB = MBd; }
    else { b -= GD; A1 = A1s; A2 = A2s; B1 = B1s; B2 = B2s; bias = bs; C = Cs; M = Ms; MB = MBs; }
    const int mi = (b >> 5) * 8 + (b & 7);
    const int ni = (b >> 3) & 3;
    if (mi >= MB) return;

    __shared__ __align__(16) u16 As[2][4][256][8];  // 32 KB
    __shared__ __align__(16) u16 Bs[2][4][128][8];  // 16 KB
    const int tid = threadIdx.x;
    const int lane = tid & 63;
    const int w = tid >> 6;             // 0..7
    const int m0 = mi * 256, n0 = ni * 128;
    const int wm = w >> 1, wn = w & 1;  // 4m x 2n waves, 64x64 each
    const int g = lane >> 4, r = lane & 15;

    const int srow = tid >> 2;          // 0..127
    const int skc  = tid & 3;           // 0..3

    f32x4 acc[4][4];
#pragma unroll
    for (int i = 0; i < 4; ++i)
#pragma unroll
        for (int j = 0; j < 4; ++j) acc[i][j] = (f32x4){0.f, 0.f, 0.f, 0.f};

    uint4 ra0, ra1, rb0;
    auto gload = [&](int kt) {
        const u16* Ap = (kt < 16) ? A1 : A2;
        const u16* Bp = (kt < 16) ? B1 : B2;
        const int kb = (kt & 15) * 32 + skc * 8;
        int r0 = m0 + srow;       if (r0 > M - 1) r0 = M - 1;
        int r1 = m0 + srow + 128; if (r1 > M - 1) r1 = M - 1;
        ra0 = *(const uint4*)(Ap + (size_t)r0 * HDIM + kb);
        ra1 = *(const uint4*)(Ap + (size_t)r1 * HDIM + kb);
        rb0 = *(const uint4*)(Bp + (size_t)(n0 + srow) * HDIM + kb);
    };
    auto swrite = [&](int buf) {
        *(uint4*)&As[buf][skc][srow][0]       = ra0;
        *(uint4*)&As[buf][skc][srow + 128][0] = ra1;
        *(uint4*)&Bs[buf][skc][srow][0]       = rb0;
    };
    auto compute = [&](int buf) {
        bf16x8 af[4], bfr[4];
#pragma unroll
        for (int i = 0; i < 4; ++i) {
            af[i]  = *(const bf16x8*)&As[buf][g][wm * 64 + i * 16 + r][0];
            bfr[i] = *(const bf16x8*)&Bs[buf][g][wn * 64 + i * 16 + r][0];
        }
#pragma unroll
        for (int i = 0; i < 4; ++i)
#pragma unroll
            for (int j = 0; j < 4; ++j)
                acc[i][j] = __builtin_amdgcn_mfma_f32_16x16x32_bf16(af[i], bfr[j], acc[i][j], 0, 0, 0);
    };

    gload(0);
    swrite(0);
    __syncthreads();
    for (int kt = 0; kt < 32; ++kt) {
        if (kt < 31) gload(kt + 1);        // global->reg, retires under compute
        compute(kt & 1);
        if (kt < 31) swrite((kt + 1) & 1); // disjoint buffer, no race
        __syncthreads();
    }

    // epilogue: 2 i-blocks per LDS staging round (ep = 4KB/wave)
    float bv[4];
#pragma unroll
    for (int j = 0; j < 4; ++j) bv[j] = bias[n0 + wn * 64 + j * 16 + r];

    u16* ep = ((u16*)As) + w * 2048;
    const int rr = lane >> 3;
    const int cc = (lane & 7) * 8;
#pragma unroll
    for (int ih = 0; ih < 2; ++ih) {
#pragma unroll
        for (int ii = 0; ii < 2; ++ii) {
            int i = ih * 2 + ii;
#pragma unroll
            for (int j = 0; j < 4; ++j)
#pragma unroll
                for (int q = 0; q < 4; ++q)
                    ep[ii * 1024 + (g * 4 + q) * 64 + j * 16 + r] =
                        f2bf(fmaxf(acc[i][j][q] + bv[j], 0.f));
        }
        __syncthreads();
#pragma unroll
        for (int ii = 0; ii < 2; ++ii) {
            int i = ih * 2 + ii;
            int row0 = m0 + wm * 64 + i * 16 + rr;
            int row1 = row0 + 8;
            uint4 v0 = *(uint4*)&ep[ii * 1024 + rr * 64 + cc];
            uint4 v1 = *(uint4*)&ep[ii * 1024 + (rr + 8) * 64 + cc];
            if (row0 < M) *(uint4*)(C + (size_t)row0 * HDIM + n0 + wn * 64 + cc) = v0;
            if (row1 < M) *(uint4*)(C + (size_t)row1 * HDIM + n0 + wn * 64 + cc) = v1;
        }
        __syncthreads();
    }
}

// ---------- in-place bf16 -> f32 widening of d_out ----------
__global__ void expand_k(float* out, int lo, int hi) {
    const u16* src = (const u16*)out;
    int j = lo + blockIdx.x * 256 + threadIdx.x;
    if (j < hi) {
        float v = bf2f(src[j]);
        out[(size_t)j] = v;
    }
}
__global__ void expand_final(float* out, int n) {
    __shared__ u16 tmp[4096];
    const u16* src = (const u16*)out;
    int tid = threadIdx.x;
    for (int i = tid; i < n; i += blockDim.x) tmp[i] = src[i];
    __syncthreads();
    for (int i = tid; i < n; i += blockDim.x) out[(size_t)i] = bf2f(tmp[i]);
}

// ---------- host orchestration ----------
extern "C" void kernel_launch(void* const* d_in, const int* in_sizes, int n_in,
                              void* d_out, int out_size, void* d_ws, size_t ws_size,
                              hipStream_t stream) {
    const float* x_s   = (const float*)d_in[0];
    const float* x_d   = (const float*)d_in[1];
    const float* W_srv = (const float*)d_in[2];
    const float* b_srv = (const float*)d_in[3];
    const float* W_dev = (const float*)d_in[4];
    const float* b_dev = (const float*)d_in[5];
    const float* Wl    = (const float*)d_in[6];
    const float* bl    = (const float*)d_in[7];
    const float* Wr    = (const float*)d_in[8];
    const int* e_sd_src = (const int*)d_in[9];
    const int* e_sd_dst = (const int*)d_in[10];
    const int* e_ds_src = (const int*)d_in[11];
    const int* e_ds_dst = (const int*)d_in[12];

    const size_t NTOT = (size_t)(NSRV + NDEV) * HDIM;
    float* fout = (float*)d_out;
    u16* u = (u16*)d_out;
    u16* hA_s = u;
    u16* hA_d = u + (size_t)NSRV * HDIM;
    u16* hB_s = u + NTOT;
    u16* hB_d = u + NTOT + (size_t)NSRV * HDIM;

    char* p = (char*)d_ws;
    auto carve = [&](size_t bytes) -> void* {
        void* ret = (void*)p;
        p += (bytes + 255) & ~(size_t)255;
        return ret;
    };
    int* cnt_d = (int*)carve((size_t)NDEV * 4);
    int* cnt_s = (int*)carve((size_t)NSRV * 4);
    int* off_d = (int*)carve((size_t)NDEV * 4);
    int* off_s = (int*)carve((size_t)NSRV * 4);
    int* cur_d = (int*)carve((size_t)NDEV * 4);
    int* cur_s = (int*)carve((size_t)NSRV * 4);
    int* src_d = (int*)carve((size_t)NEDGE * 4);
    int* src_s = (int*)carve((size_t)NEDGE * 4);
    int* csum_d = (int*)carve(64 * 4);
    int* csum_s = (int*)carve(64 * 4);
    int* csx_d  = (int*)carve(64 * 4);
    int* csx_s  = (int*)carve(64 * 4);
    u16* WlT   = (u16*)carve((size_t)NLAY * 2 * HDIM * HDIM * 2);
    u16* WrT   = (u16*)carve((size_t)NLAY * 2 * HDIM * HDIM * 2);
    u16* agg_d = (u16*)carve((size_t)NDEV * HDIM * 2);
    u16* agg_s = (u16*)carve((size_t)NSRV * HDIM * 2);
    u16* xb_s  = (u16*)carve((size_t)NSRV * 64 * 2);
    u16* xb_d  = (u16*)carve((size_t)NDEV * 32 * 2);
    u16* WTp_s = (u16*)carve((size_t)HDIM * 64 * 2);
    u16* WTp_d = (u16*)carve((size_t)HDIM * 32 * 2);

    hipMemsetAsync(cnt_d, 0, (size_t)NDEV * 4, stream);
    hipMemsetAsync(cnt_s, 0, (size_t)NSRV * 4, stream);

    cast_bf16<<<(NSRV * 64 / 2 + 255) / 256, 256, 0, stream>>>(x_s, xb_s, NSRV * 64 / 2);
    cast_bf16<<<(NDEV * 32 / 2 + 255) / 256, 256, 0, stream>>>(x_d, xb_d, NDEV * 32 / 2);
    transpose_wp<64><<<dim3(16, 2), dim3(32, 8), 0, stream>>>(W_srv, WTp_s);
    transpose_wp<32><<<dim3(16, 1), dim3(32, 8), 0, stream>>>(W_dev, WTp_d);
    transpose_w<<<dim3(16, 16, 16), dim3(32, 8), 0, stream>>>(Wl, Wr, WlT, WrT);

    proj_gemm<64><<<dim3((NSRV + 127) / 128, 4), 256, 0, stream>>>(xb_s, WTp_s, b_srv, hA_s, NSRV);
    proj_gemm<32><<<dim3((NDEV + 127) / 128, 4), 256, 0, stream>>>(xb_d, WTp_d, b_dev, hA_d, NDEV);

    count_k<<<(2 * NEDGE + 255) / 256, 256, 0, stream>>>(e_sd_dst, e_ds_dst, cnt_d, cnt_s);
    scan_a_both<<<NCH_D + NCH_S, 256, 0, stream>>>(cnt_d, off_d, csum_d, cnt_s, off_s, csum_s);
    scan_k<<<2, 64, 0, stream>>>(csum_d, csx_d, csx_d, NCH_D, csum_s, csx_s, csx_s, NCH_S);
    scan_c_both<<<(NDEV + NSRV + 255) / 256, 256, 0, stream>>>(off_d, cur_d, csx_d, off_s, cur_s, csx_s);
    fill_k<<<(2 * NEDGE + 255) / 256, 256, 0, stream>>>(e_sd_src, e_sd_dst, cur_d, src_d,
                                                        e_ds_src, e_ds_dst, cur_s, src_s);

    const int MB_D = (NDEV + 255) / 256;       // 196
    const int MB_S = (NSRV + 255) / 256;       // 40
    const int GD = ((MB_D + 7) / 8) * 32;      // 800
    const int GS = ((MB_S + 7) / 8) * 32;      // 160

    for (int l = 0; l < NLAY; ++l) {
        const u16* hs_in = (l & 1) ? hB_s : hA_s;
        const u16* hd_in = (l & 1) ? hB_d : hA_d;
        u16* hs_out = (l & 1) ? hA_s : hB_s;
        u16* hd_out = (l & 1) ? hA_d : hB_d;

        const u16* WlT0 = WlT + (size_t)(l * 2 + 0) * HDIM * HDIM;
        const u16* WrT0 = WrT + (size_t)(l * 2 + 0) * HDIM * HDIM;
        const u16* WlT1 = WlT + (size_t)(l * 2 + 1) * HDIM * HDIM;
        const u16* WrT1 = WrT + (size_t)(l * 2 + 1) * HDIM * HDIM;
        const float* bl0 = bl + (size_t)(l * 2 + 0) * HDIM;
        const float* bl1 = bl + (size_t)(l * 2 + 1) * HDIM;

        aggregate_both<<<(NDEV + NSRV + 3) / 4, 256, 0, stream>>>(
            hs_in, hd_in, off_d, cnt_d, src_d, off_s, cnt_s, src_s, agg_d, agg_s);
        gemm_both<<<GD + GS, 512, 0, stream>>>(
            agg_d, hd_in, WlT0, WrT0, bl0, hd_out, NDEV, MB_D, GD,
            agg_s, hs_in, WlT1, WrT1, bl1, hs_out, NSRV, MB_S);
    }

    int hi = (int)NTOT;
    while (hi > 4000 && (hi % 2 == 0)) {
        int lo = hi / 2;
        int nblk = (hi - lo + 255) / 256;
        expand_k<<<nblk, 256, 0, stream>>>(fout, lo, hi);
        hi = lo;
    }
    expand_final<<<1, 512, 0, stream>>>(fout, hi);
}

// Round 17
// 837.099 us; speedup vs baseline: 1.6941x; 1.0238x over previous
//
#include <hip/hip_runtime.h>
#include <cstdint>

#define NSRV 10000
#define NDEV 50000
#define HDIM 512
#define NEDGE 300000
#define NLAY 4
#define SCHUNK 2048
#define NCH_D ((NDEV + SCHUNK - 1) / SCHUNK)  // 25
#define NCH_S ((NSRV + SCHUNK - 1) / SCHUNK)  // 5

typedef unsigned int u32;
typedef unsigned short u16;

typedef __bf16 bf16x8 __attribute__((ext_vector_type(8)));
typedef float f32x4 __attribute__((ext_vector_type(4)));

// ---------- bf16 helpers ----------
__device__ __forceinline__ float bflo(u32 u) { return __uint_as_float(u << 16); }
__device__ __forceinline__ float bfhi(u32 u) { return __uint_as_float(u & 0xffff0000u); }
__device__ __forceinline__ float bf2f(u16 v) { return __uint_as_float((u32)v << 16); }
__device__ __forceinline__ u16 f2bf(float f) {
    u32 u = __float_as_uint(f);
    u += 0x7fffu + ((u >> 16) & 1u);  // RNE
    return (u16)(u >> 16);
}
__device__ __forceinline__ u32 pack2(float a, float b) {
    return (u32)f2bf(a) | ((u32)f2bf(b) << 16);
}
__device__ __forceinline__ u32 relu2(u32 v) {
    return pack2(fmaxf(bflo(v), 0.f), fmaxf(bfhi(v), 0.f));
}
__device__ __forceinline__ u32 addrelu2(u32 v, u32 a) {
    return pack2(fmaxf(bflo(v) + bflo(a), 0.f), fmaxf(bfhi(v) + bfhi(a), 0.f));
}

// ---------- f32 -> bf16 cast ----------
__global__ void cast_bf16(const float* __restrict__ src, u16* __restrict__ dst, int n2) {
    int i = blockIdx.x * 256 + threadIdx.x;
    if (i < n2) {
        float2 v = *(const float2*)(src + 2 * (size_t)i);
        *(u32*)(dst + 2 * (size_t)i) = pack2(v.x, v.y);
    }
}

// ---------- weight transpose + bf16 cast (512x512 x16 matrices) ----------
__global__ void transpose_w(const float* __restrict__ Wl, const float* __restrict__ Wr,
                            u16* __restrict__ WlT, u16* __restrict__ WrT) {
    __shared__ float t[32][33];
    int z = blockIdx.z;
    const float* Wsrc = ((z < 8) ? Wl : Wr) + (size_t)(z & 7) * HDIM * HDIM;
    u16* Wdst = ((z < 8) ? WlT : WrT) + (size_t)(z & 7) * HDIM * HDIM;
    int n0 = blockIdx.x * 32, k0 = blockIdx.y * 32;
    int x = threadIdx.x, y = threadIdx.y;
#pragma unroll
    for (int i = 0; i < 4; ++i)
        t[y + 8 * i][x] = Wsrc[(size_t)(k0 + y + 8 * i) * HDIM + n0 + x];
    __syncthreads();
    if (x < 16) {
#pragma unroll
        for (int i = 0; i < 4; ++i) {
            int n = n0 + y + 8 * i;
            u32 v = pack2(t[2 * x][y + 8 * i], t[2 * x + 1][y + 8 * i]);
            *(u32*)(Wdst + (size_t)n * HDIM + k0 + 2 * x) = v;
        }
    }
}

// ---------- proj weight transpose: W[K][512] f32 -> WT[512][K] bf16 ----------
template <int K>
__global__ void transpose_wp(const float* __restrict__ W, u16* __restrict__ WT) {
    __shared__ float t[32][33];
    int n0 = blockIdx.x * 32, k0 = blockIdx.y * 32;
    int x = threadIdx.x, y = threadIdx.y;
#pragma unroll
    for (int i = 0; i < 4; ++i)
        t[y + 8 * i][x] = W[(size_t)(k0 + y + 8 * i) * HDIM + n0 + x];
    __syncthreads();
    if (x < 16) {
#pragma unroll
        for (int i = 0; i < 4; ++i) {
            int n = n0 + y + 8 * i;
            u32 v = pack2(t[2 * x][y + 8 * i], t[2 * x + 1][y + 8 * i]);
            *(u32*)(WT + (size_t)n * K + k0 + 2 * x) = v;
        }
    }
}

// ---------- MFMA projection (input layer) ----------
template <int KTOT>
__launch_bounds__(256, 2)
__global__ void proj_gemm(const u16* __restrict__ A, const u16* __restrict__ B,
                          const float* __restrict__ bias, u16* __restrict__ C, int M) {
    constexpr int NKC = KTOT / 8;
    __shared__ __align__(16) u16 As[NKC][128][8];
    __shared__ __align__(16) u16 Bs[NKC][128][8];
    const int tid = threadIdx.x;
    const int lane = tid & 63;
    const int w = tid >> 6;
    const int m0 = blockIdx.x * 128, n0 = blockIdx.y * 128;
    const int wm = w >> 1, wn = w & 1;
    const int g = lane >> 4, r = lane & 15;

    for (int idx = tid; idx < NKC * 128; idx += 256) {
        int row = idx / NKC, kc = idx % NKC;
        int ra = m0 + row; if (ra > M - 1) ra = M - 1;
        *(uint4*)&As[kc][row][0] = *(const uint4*)(A + (size_t)ra * KTOT + kc * 8);
        *(uint4*)&Bs[kc][row][0] = *(const uint4*)(B + (size_t)(n0 + row) * KTOT + kc * 8);
    }
    __syncthreads();

    f32x4 acc[4][4];
#pragma unroll
    for (int i = 0; i < 4; ++i)
#pragma unroll
        for (int j = 0; j < 4; ++j) acc[i][j] = (f32x4){0.f, 0.f, 0.f, 0.f};

#pragma unroll
    for (int t = 0; t < KTOT / 32; ++t) {
        bf16x8 af[4], bfr[4];
#pragma unroll
        for (int i = 0; i < 4; ++i) {
            af[i]  = *(const bf16x8*)&As[t * 4 + g][wm * 64 + i * 16 + r][0];
            bfr[i] = *(const bf16x8*)&Bs[t * 4 + g][wn * 64 + i * 16 + r][0];
        }
#pragma unroll
        for (int i = 0; i < 4; ++i)
#pragma unroll
            for (int j = 0; j < 4; ++j)
                acc[i][j] = __builtin_amdgcn_mfma_f32_16x16x32_bf16(af[i], bfr[j], acc[i][j], 0, 0, 0);
    }
    __syncthreads();

    float bv[4];
#pragma unroll
    for (int j = 0; j < 4; ++j) bv[j] = bias[n0 + wn * 64 + j * 16 + r];

    u16* ep = ((u16*)As) + w * 1024;
    const int rr = lane >> 3;
    const int cc = (lane & 7) * 8;
#pragma unroll
    for (int i = 0; i < 4; ++i) {
#pragma unroll
        for (int j = 0; j < 4; ++j)
#pragma unroll
            for (int q = 0; q < 4; ++q)
                ep[(g * 4 + q) * 64 + j * 16 + r] = f2bf(acc[i][j][q] + bv[j]);
        __syncthreads();
        int row0 = m0 + wm * 64 + i * 16 + rr;
        int row1 = row0 + 8;
        uint4 v0 = *(uint4*)&ep[rr * 64 + cc];
        uint4 v1 = *(uint4*)&ep[(rr + 8) * 64 + cc];
        if (row0 < M) *(uint4*)(C + (size_t)row0 * HDIM + n0 + wn * 64 + cc) = v0;
        if (row1 < M) *(uint4*)(C + (size_t)row1 * HDIM + n0 + wn * 64 + cc) = v1;
        __syncthreads();
    }
}

// ---------- plain 128x128 GEMM, K=512: C = A @ B^T (no bias/relu), for ps = hs @ Wl ----------
__launch_bounds__(256, 2)
__global__ void gemm_plain(const u16* __restrict__ A, const u16* __restrict__ B,
                           u16* __restrict__ C, int M, int MB) {
    const int b = blockIdx.x;
    const int mi = (b >> 5) * 8 + (b & 7);
    const int ni = (b >> 3) & 3;
    if (mi >= MB) return;

    __shared__ __align__(16) u16 As[2][4][128][8];
    __shared__ __align__(16) u16 Bs[2][4][128][8];
    const int tid = threadIdx.x;
    const int lane = tid & 63;
    const int w = tid >> 6;
    const int m0 = mi * 128, n0 = ni * 128;
    const int wm = w >> 1, wn = w & 1;
    const int g = lane >> 4, r = lane & 15;

    const int srow = tid >> 2;  // 0..63
    const int skc  = tid & 3;   // 0..3

    f32x4 acc[4][4];
#pragma unroll
    for (int i = 0; i < 4; ++i)
#pragma unroll
        for (int j = 0; j < 4; ++j) acc[i][j] = (f32x4){0.f, 0.f, 0.f, 0.f};

    uint4 ra0, ra1, rb0, rb1;
    auto gload = [&](int kt) {
        const int kb = kt * 32 + skc * 8;
        int r0 = m0 + srow;      if (r0 > M - 1) r0 = M - 1;
        int r1 = m0 + srow + 64; if (r1 > M - 1) r1 = M - 1;
        ra0 = *(const uint4*)(A + (size_t)r0 * HDIM + kb);
        ra1 = *(const uint4*)(A + (size_t)r1 * HDIM + kb);
        rb0 = *(const uint4*)(B + (size_t)(n0 + srow) * HDIM + kb);
        rb1 = *(const uint4*)(B + (size_t)(n0 + srow + 64) * HDIM + kb);
    };
    auto swrite = [&](int buf) {
        *(uint4*)&As[buf][skc][srow][0]      = ra0;
        *(uint4*)&As[buf][skc][srow + 64][0] = ra1;
        *(uint4*)&Bs[buf][skc][srow][0]      = rb0;
        *(uint4*)&Bs[buf][skc][srow + 64][0] = rb1;
    };
    auto compute = [&](int buf) {
        bf16x8 af[4], bfr[4];
#pragma unroll
        for (int i = 0; i < 4; ++i) {
            af[i]  = *(const bf16x8*)&As[buf][g][wm * 64 + i * 16 + r][0];
            bfr[i] = *(const bf16x8*)&Bs[buf][g][wn * 64 + i * 16 + r][0];
        }
#pragma unroll
        for (int i = 0; i < 4; ++i)
#pragma unroll
            for (int j = 0; j < 4; ++j)
                acc[i][j] = __builtin_amdgcn_mfma_f32_16x16x32_bf16(af[i], bfr[j], acc[i][j], 0, 0, 0);
    };

    gload(0);
    swrite(0);
    __syncthreads();
    for (int kt = 0; kt < 16; ++kt) {  // K = 512
        if (kt < 15) gload(kt + 1);
        compute(kt & 1);
        if (kt < 15) swrite((kt + 1) & 1);
        __syncthreads();
    }

    u16* ep = ((u16*)As) + w * 1024;
    const int rr = lane >> 3;
    const int cc = (lane & 7) * 8;
#pragma unroll
    for (int i = 0; i < 4; ++i) {
#pragma unroll
        for (int j = 0; j < 4; ++j)
#pragma unroll
            for (int q = 0; q < 4; ++q)
                ep[(g * 4 + q) * 64 + j * 16 + r] = f2bf(acc[i][j][q]);
        __syncthreads();
        int row0 = m0 + wm * 64 + i * 16 + rr;
        int row1 = row0 + 8;
        uint4 v0 = *(uint4*)&ep[rr * 64 + cc];
        uint4 v1 = *(uint4*)&ep[(rr + 8) * 64 + cc];
        if (row0 < M) *(uint4*)(C + (size_t)row0 * HDIM + n0 + wn * 64 + cc) = v0;
        if (row1 < M) *(uint4*)(C + (size_t)row1 * HDIM + n0 + wn * 64 + cc) = v1;
        __syncthreads();
    }
}

// ---------- CSR build ----------
__global__ void count_k(const int* __restrict__ d_sd, const int* __restrict__ d_ds,
                        int* __restrict__ cd, int* __restrict__ cs) {
    int i = blockIdx.x * 256 + threadIdx.x;
    if (i < NEDGE) atomicAdd(&cd[d_sd[i]], 1);
    else if (i < 2 * NEDGE) atomicAdd(&cs[d_ds[i - NEDGE]], 1);
}

__global__ void scan_a_both(const int* __restrict__ cd, int* __restrict__ od, int* __restrict__ csd,
                            const int* __restrict__ cs, int* __restrict__ os, int* __restrict__ css) {
    __shared__ int wsum[4];
    int blk = blockIdx.x;
    const int* c; int* o; int* csum; int n; int cb;
    if (blk < NCH_D) { c = cd; o = od; csum = csd; n = NDEV; cb = blk; }
    else             { c = cs; o = os; csum = css; n = NSRV; cb = blk - NCH_D; }
    int tid = threadIdx.x;
    int base = cb * SCHUNK;
    int idx0 = base + tid * 8;
    int v[8];
    int s = 0;
#pragma unroll
    for (int i = 0; i < 8; ++i) {
        int idx = idx0 + i;
        v[i] = (idx < n) ? c[idx] : 0;
        s += v[i];
    }
    int lane = tid & 63, wv = tid >> 6;
    int ss = s;
#pragma unroll
    for (int off = 1; off < 64; off <<= 1) {
        int t = __shfl_up(ss, off);
        if (lane >= off) ss += t;
    }
    if (lane == 63) wsum[wv] = ss;
    __syncthreads();
    int woff = 0;
#pragma unroll
    for (int i = 0; i < 4; ++i)
        if (i < wv) woff += wsum[i];
    int ex = woff + ss - s;
#pragma unroll
    for (int i = 0; i < 8; ++i) {
        int idx = idx0 + i;
        if (idx < n) o[idx] = ex;
        ex += v[i];
    }
    if (tid == 255) csum[cb] = woff + ss;
}

__global__ void scan_k(const int* __restrict__ cA, int* __restrict__ oA, int* __restrict__ uA, int nA,
                       const int* __restrict__ cB, int* __restrict__ oB, int* __restrict__ uB, int nB) {
    const int* c; int* o; int* u; int n;
    if (blockIdx.x == 0) { c = cA; o = oA; u = uA; n = nA; }
    else                 { c = cB; o = oB; u = uB; n = nB; }
    int lane = threadIdx.x;
    int carry = 0;
    for (int base = 0; base < n; base += 64) {
        int idx = base + lane;
        int v = (idx < n) ? c[idx] : 0;
        int s = v;
#pragma unroll
        for (int off = 1; off < 64; off <<= 1) {
            int t = __shfl_up(s, off);
            if (lane >= off) s += t;
        }
        if (idx < n) { int ex = carry + s - v; o[idx] = ex; u[idx] = ex; }
        carry += __shfl(s, 63);
    }
}

__global__ void scan_c_both(int* __restrict__ od, int* __restrict__ curd, const int* __restrict__ csxd,
                            int* __restrict__ os, int* __restrict__ curs, const int* __restrict__ csxs) {
    int i = blockIdx.x * 256 + threadIdx.x;
    if (i < NDEV) {
        int v = od[i] + csxd[i / SCHUNK];
        od[i] = v;
        curd[i] = v;
    } else if (i < NDEV + NSRV) {
        int j = i - NDEV;
        int v = os[j] + csxs[j / SCHUNK];
        os[j] = v;
        curs[j] = v;
    }
}

__global__ void fill_k(const int* __restrict__ s_sd, const int* __restrict__ d_sd,
                       int* __restrict__ cur_d, int* __restrict__ srcs_d,
                       const int* __restrict__ s_ds, const int* __restrict__ d_ds,
                       int* __restrict__ cur_s, int* __restrict__ srcs_s) {
    int i = blockIdx.x * 256 + threadIdx.x;
    if (i < NEDGE) {
        int p = atomicAdd(&cur_d[d_sd[i]], 1);
        srcs_d[p] = s_sd[i];
    } else if (i < 2 * NEDGE) {
        int j = i - NEDGE;
        int p = atomicAdd(&cur_s[d_ds[j]], 1);
        srcs_s[p] = s_ds[j];
    }
}

// ---------- fused scatter-mean, 8-wide MLP ----------
// dev dsts gather from ps (= hs @ Wl, projected-first); srv dsts gather from hd
__global__ void aggregate_both(const u16* __restrict__ ps, const u16* __restrict__ hd,
                               const int* __restrict__ offs_d, const int* __restrict__ cnt_d,
                               const int* __restrict__ src_d,
                               const int* __restrict__ offs_s, const int* __restrict__ cnt_s,
                               const int* __restrict__ src_s,
                               u16* __restrict__ agg_d, u16* __restrict__ agg_s) {
    int wv = threadIdx.x >> 6, lane = threadIdx.x & 63;
    int d = blockIdx.x * 4 + wv;
    const u16* h; const int* offs; const int* cnt; const int* srcs; u16* agg; int idx;
    if (d < NDEV)              { h = ps; offs = offs_d; cnt = cnt_d; srcs = src_d; agg = agg_d; idx = d; }
    else if (d < NDEV + NSRV)  { h = hd; offs = offs_s; cnt = cnt_s; srcs = src_s; agg = agg_s; idx = d - NDEV; }
    else return;
    int beg = offs[idx], deg = cnt[idx];
    float acc[8] = {0.f, 0.f, 0.f, 0.f, 0.f, 0.f, 0.f, 0.f};
    const size_t lanecol = (size_t)lane * 8;
    auto accum = [&](const uint4& q) {
        acc[0] += bflo(q.x); acc[1] += bfhi(q.x);
        acc[2] += bflo(q.y); acc[3] += bfhi(q.y);
        acc[4] += bflo(q.z); acc[5] += bfhi(q.z);
        acc[6] += bflo(q.w); acc[7] += bfhi(q.w);
    };
    for (int t0 = 0; t0 < deg; t0 += 64) {
        int nch = min(64, deg - t0);
        int sv = (t0 + lane < deg) ? srcs[beg + t0 + lane] : 0;
        int j = 0;
        for (; j + 8 <= nch; j += 8) {
            uint4 q[8];
#pragma unroll
            for (int u_ = 0; u_ < 8; ++u_) {
                int s = __shfl(sv, j + u_);
                q[u_] = *(const uint4*)(h + (size_t)s * HDIM + lanecol);
            }
#pragma unroll
            for (int u_ = 0; u_ < 8; ++u_) accum(q[u_]);
        }
        for (; j + 4 <= nch; j += 4) {
            uint4 q[4];
#pragma unroll
            for (int u_ = 0; u_ < 4; ++u_) {
                int s = __shfl(sv, j + u_);
                q[u_] = *(const uint4*)(h + (size_t)s * HDIM + lanecol);
            }
#pragma unroll
            for (int u_ = 0; u_ < 4; ++u_) accum(q[u_]);
        }
        for (; j < nch; ++j) {
            int s = __shfl(sv, j);
            const uint4 q = *(const uint4*)(h + (size_t)s * HDIM + lanecol);
            accum(q);
        }
    }
    float sc = 1.f / (float)(deg > 0 ? deg : 1);
    uint4 o;
    o.x = pack2(acc[0] * sc, acc[1] * sc);
    o.y = pack2(acc[2] * sc, acc[3] * sc);
    o.z = pack2(acc[4] * sc, acc[5] * sc);
    o.w = pack2(acc[6] * sc, acc[7] * sc);
    *(uint4*)(agg + (size_t)idx * HDIM + lanecol) = o;
}

// ---------- fused SAGE GEMM 256x128 (r13 schedule), per-segment kt0 + epilogue-agg ----------
// dev: kt0=16 (only A2=hd @ B2=Wr, K=512) + AGG=agg_d added before relu in epilogue.
// srv: kt0=0  (A1=agg_s @ B1=Wl then A2=hs @ B2=Wr, K=1024), AGG=null.
__launch_bounds__(512, 2)
__global__ void gemm_both(const u16* __restrict__ A1d, const u16* __restrict__ A2d,
                          const u16* __restrict__ B1d, const u16* __restrict__ B2d,
                          const u16* __restrict__ AGGd, const float* __restrict__ bd,
                          u16* __restrict__ Cd, int Md, int MBd, int GD,
                          const u16* __restrict__ A1s, const u16* __restrict__ A2s,
                          const u16* __restrict__ B1s, const u16* __restrict__ B2s,
                          const float* __restrict__ bs, u16* __restrict__ Cs, int Ms, int MBs) {
    int b = blockIdx.x;
    const u16 *A1, *A2, *B1, *B2, *AGG; const float* bias; u16* C; int M, MB, kt0;
    if (b < GD) {
        A1 = A1d; A2 = A2d; B1 = B1d; B2 = B2d; AGG = AGGd;
        bias = bd; C = Cd; M = Md; MB = MBd; kt0 = 16;
    } else {
        b -= GD;
        A1 = A1s; A2 = A2s; B1 = B1s; B2 = B2s; AGG = nullptr;
        bias = bs; C = Cs; M = Ms; MB = MBs; kt0 = 0;
    }
    const int mi = (b >> 5) * 8 + (b & 7);
    const int ni = (b >> 3) & 3;
    if (mi >= MB) return;

    __shared__ __align__(16) u16 As[2][4][256][8];  // 32 KB
    __shared__ __align__(16) u16 Bs[2][4][128][8];  // 16 KB
    const int tid = threadIdx.x;
    const int lane = tid & 63;
    const int w = tid >> 6;             // 0..7
    const int m0 = mi * 256, n0 = ni * 128;
    const int wm = w >> 1, wn = w & 1;  // 4m x 2n waves, 64x64 each
    const int g = lane >> 4, r = lane & 15;

    const int srow = tid >> 2;          // 0..127
    const int skc  = tid & 3;           // 0..3

    f32x4 acc[4][4];
#pragma unroll
    for (int i = 0; i < 4; ++i)
#pragma unroll
        for (int j = 0; j < 4; ++j) acc[i][j] = (f32x4){0.f, 0.f, 0.f, 0.f};

    uint4 ra0, ra1, rb0;
    auto gload = [&](int kt) {
        const u16* Ap = (kt < 16) ? A1 : A2;
        const u16* Bp = (kt < 16) ? B1 : B2;
        const int kb = (kt & 15) * 32 + skc * 8;
        int r0 = m0 + srow;       if (r0 > M - 1) r0 = M - 1;
        int r1 = m0 + srow + 128; if (r1 > M - 1) r1 = M - 1;
        ra0 = *(const uint4*)(Ap + (size_t)r0 * HDIM + kb);
        ra1 = *(const uint4*)(Ap + (size_t)r1 * HDIM + kb);
        rb0 = *(const uint4*)(Bp + (size_t)(n0 + srow) * HDIM + kb);
    };
    auto swrite = [&](int buf) {
        *(uint4*)&As[buf][skc][srow][0]       = ra0;
        *(uint4*)&As[buf][skc][srow + 128][0] = ra1;
        *(uint4*)&Bs[buf][skc][srow][0]       = rb0;
    };
    auto compute = [&](int buf) {
        bf16x8 af[4], bfr[4];
#pragma unroll
        for (int i = 0; i < 4; ++i) {
            af[i]  = *(const bf16x8*)&As[buf][g][wm * 64 + i * 16 + r][0];
            bfr[i] = *(const bf16x8*)&Bs[buf][g][wn * 64 + i * 16 + r][0];
        }
#pragma unroll
        for (int i = 0; i < 4; ++i)
#pragma unroll
            for (int j = 0; j < 4; ++j)
                acc[i][j] = __builtin_amdgcn_mfma_f32_16x16x32_bf16(af[i], bfr[j], acc[i][j], 0, 0, 0);
    };

    gload(kt0);
    swrite(0);  // kt0 is 0 or 16, both even -> buf0
    __syncthreads();
    for (int kt = kt0; kt < 32; ++kt) {
        if (kt < 31) gload(kt + 1);        // global->reg, retires under compute
        compute(kt & 1);
        if (kt < 31) swrite((kt + 1) & 1); // disjoint buffer, no race
        __syncthreads();
    }

    // epilogue: pre-activation (acc+bias) -> LDS transpose -> [+agg] -> relu -> store
    float bv[4];
#pragma unroll
    for (int j = 0; j < 4; ++j) bv[j] = bias[n0 + wn * 64 + j * 16 + r];

    u16* ep = ((u16*)As) + w * 2048;
    const int rr = lane >> 3;
    const int cc = (lane & 7) * 8;
#pragma unroll
    for (int ih = 0; ih < 2; ++ih) {
#pragma unroll
        for (int ii = 0; ii < 2; ++ii) {
            int i = ih * 2 + ii;
#pragma unroll
            for (int j = 0; j < 4; ++j)
#pragma unroll
                for (int q = 0; q < 4; ++q)
                    ep[ii * 1024 + (g * 4 + q) * 64 + j * 16 + r] =
                        f2bf(acc[i][j][q] + bv[j]);
        }
        __syncthreads();
#pragma unroll
        for (int ii = 0; ii < 2; ++ii) {
            int i = ih * 2 + ii;
            int row0 = m0 + wm * 64 + i * 16 + rr;
            int row1 = row0 + 8;
            uint4 v0 = *(uint4*)&ep[ii * 1024 + rr * 64 + cc];
            uint4 v1 = *(uint4*)&ep[ii * 1024 + (rr + 8) * 64 + cc];
            size_t c0 = (size_t)row0 * HDIM + n0 + wn * 64 + cc;
            size_t c1 = (size_t)row1 * HDIM + n0 + wn * 64 + cc;
            if (row0 < M) {
                uint4 o;
                if (AGG) {
                    uint4 a = *(const uint4*)(AGG + c0);
                    o.x = addrelu2(v0.x, a.x); o.y = addrelu2(v0.y, a.y);
                    o.z = addrelu2(v0.z, a.z); o.w = addrelu2(v0.w, a.w);
                } else {
                    o.x = relu2(v0.x); o.y = relu2(v0.y);
                    o.z = relu2(v0.z); o.w = relu2(v0.w);
                }
                *(uint4*)(C + c0) = o;
            }
            if (row1 < M) {
                uint4 o;
                if (AGG) {
                    uint4 a = *(const uint4*)(AGG + c1);
                    o.x = addrelu2(v1.x, a.x); o.y = addrelu2(v1.y, a.y);
                    o.z = addrelu2(v1.z, a.z); o.w = addrelu2(v1.w, a.w);
                } else {
                    o.x = relu2(v1.x); o.y = relu2(v1.y);
                    o.z = relu2(v1.z); o.w = relu2(v1.w);
                }
                *(uint4*)(C + c1) = o;
            }
        }
        __syncthreads();
    }
}

// ---------- in-place bf16 -> f32 widening of d_out ----------
__global__ void expand_k(float* out, int lo, int hi) {
    const u16* src = (const u16*)out;
    int j = lo + blockIdx.x * 256 + threadIdx.x;
    if (j < hi) {
        float v = bf2f(src[j]);
        out[(size_t)j] = v;
    }
}
__global__ void expand_final(float* out, int n) {
    __shared__ u16 tmp[4096];
    const u16* src = (const u16*)out;
    int tid = threadIdx.x;
    for (int i = tid; i < n; i += blockDim.x) tmp[i] = src[i];
    __syncthreads();
    for (int i = tid; i < n; i += blockDim.x) out[(size_t)i] = bf2f(tmp[i]);
}

// ---------- host orchestration ----------
extern "C" void kernel_launch(void* const* d_in, const int* in_sizes, int n_in,
                              void* d_out, int out_size, void* d_ws, size_t ws_size,
                              hipStream_t stream) {
    const float* x_s   = (const float*)d_in[0];
    const float* x_d   = (const float*)d_in[1];
    const float* W_srv = (const float*)d_in[2];
    const float* b_srv = (const float*)d_in[3];
    const float* W_dev = (const float*)d_in[4];
    const float* b_dev = (const float*)d_in[5];
    const float* Wl    = (const float*)d_in[6];
    const float* bl    = (const float*)d_in[7];
    const float* Wr    = (const float*)d_in[8];
    const int* e_sd_src = (const int*)d_in[9];
    const int* e_sd_dst = (const int*)d_in[10];
    const int* e_ds_src = (const int*)d_in[11];
    const int* e_ds_dst = (const int*)d_in[12];

    const size_t NTOT = (size_t)(NSRV + NDEV) * HDIM;
    float* fout = (float*)d_out;
    u16* u = (u16*)d_out;
    u16* hA_s = u;
    u16* hA_d = u + (size_t)NSRV * HDIM;
    u16* hB_s = u + NTOT;
    u16* hB_d = u + NTOT + (size_t)NSRV * HDIM;

    char* p = (char*)d_ws;
    auto carve = [&](size_t bytes) -> void* {
        void* ret = (void*)p;
        p += (bytes + 255) & ~(size_t)255;
        return ret;
    };
    int* cnt_d = (int*)carve((size_t)NDEV * 4);
    int* cnt_s = (int*)carve((size_t)NSRV * 4);
    int* off_d = (int*)carve((size_t)NDEV * 4);
    int* off_s = (int*)carve((size_t)NSRV * 4);
    int* cur_d = (int*)carve((size_t)NDEV * 4);
    int* cur_s = (int*)carve((size_t)NSRV * 4);
    int* src_d = (int*)carve((size_t)NEDGE * 4);
    int* src_s = (int*)carve((size_t)NEDGE * 4);
    int* csum_d = (int*)carve(64 * 4);
    int* csum_s = (int*)carve(64 * 4);
    int* csx_d  = (int*)carve(64 * 4);
    int* csx_s  = (int*)carve(64 * 4);
    u16* WlT   = (u16*)carve((size_t)NLAY * 2 * HDIM * HDIM * 2);
    u16* WrT   = (u16*)carve((size_t)NLAY * 2 * HDIM * HDIM * 2);
    u16* agg_d = (u16*)carve((size_t)NDEV * HDIM * 2);
    u16* agg_s = (u16*)carve((size_t)NSRV * HDIM * 2);
    u16* ps    = (u16*)carve((size_t)NSRV * HDIM * 2);   // hs @ Wl0 (projected-first)
    u16* xb_s  = (u16*)carve((size_t)NSRV * 64 * 2);
    u16* xb_d  = (u16*)carve((size_t)NDEV * 32 * 2);
    u16* WTp_s = (u16*)carve((size_t)HDIM * 64 * 2);
    u16* WTp_d = (u16*)carve((size_t)HDIM * 32 * 2);

    hipMemsetAsync(cnt_d, 0, (size_t)NDEV * 4, stream);
    hipMemsetAsync(cnt_s, 0, (size_t)NSRV * 4, stream);

    cast_bf16<<<(NSRV * 64 / 2 + 255) / 256, 256, 0, stream>>>(x_s, xb_s, NSRV * 64 / 2);
    cast_bf16<<<(NDEV * 32 / 2 + 255) / 256, 256, 0, stream>>>(x_d, xb_d, NDEV * 32 / 2);
    transpose_wp<64><<<dim3(16, 2), dim3(32, 8), 0, stream>>>(W_srv, WTp_s);
    transpose_wp<32><<<dim3(16, 1), dim3(32, 8), 0, stream>>>(W_dev, WTp_d);
    transpose_w<<<dim3(16, 16, 16), dim3(32, 8), 0, stream>>>(Wl, Wr, WlT, WrT);

    proj_gemm<64><<<dim3((NSRV + 127) / 128, 4), 256, 0, stream>>>(xb_s, WTp_s, b_srv, hA_s, NSRV);
    proj_gemm<32><<<dim3((NDEV + 127) / 128, 4), 256, 0, stream>>>(xb_d, WTp_d, b_dev, hA_d, NDEV);

    count_k<<<(2 * NEDGE + 255) / 256, 256, 0, stream>>>(e_sd_dst, e_ds_dst, cnt_d, cnt_s);
    scan_a_both<<<NCH_D + NCH_S, 256, 0, stream>>>(cnt_d, off_d, csum_d, cnt_s, off_s, csum_s);
    scan_k<<<2, 64, 0, stream>>>(csum_d, csx_d, csx_d, NCH_D, csum_s, csx_s, csx_s, NCH_S);
    scan_c_both<<<(NDEV + NSRV + 255) / 256, 256, 0, stream>>>(off_d, cur_d, csx_d, off_s, cur_s, csx_s);
    fill_k<<<(2 * NEDGE + 255) / 256, 256, 0, stream>>>(e_sd_src, e_sd_dst, cur_d, src_d,
                                                        e_ds_src, e_ds_dst, cur_s, src_s);

    const int MB_D = (NDEV + 255) / 256;       // 196
    const int MB_S = (NSRV + 255) / 256;       // 40
    const int GD = ((MB_D + 7) / 8) * 32;      // 800
    const int GS = ((MB_S + 7) / 8) * 32;      // 160
    const int MB_P = (NSRV + 127) / 128;       // 79
    const int GP = ((MB_P + 7) / 8) * 32;      // 320

    for (int l = 0; l < NLAY; ++l) {
        const u16* hs_in = (l & 1) ? hB_s : hA_s;
        const u16* hd_in = (l & 1) ? hB_d : hA_d;
        u16* hs_out = (l & 1) ? hA_s : hB_s;
        u16* hd_out = (l & 1) ? hA_d : hB_d;

        const u16* WlT0 = WlT + (size_t)(l * 2 + 0) * HDIM * HDIM;
        const u16* WrT0 = WrT + (size_t)(l * 2 + 0) * HDIM * HDIM;
        const u16* WlT1 = WlT + (size_t)(l * 2 + 1) * HDIM * HDIM;
        const u16* WrT1 = WrT + (size_t)(l * 2 + 1) * HDIM * HDIM;
        const float* bl0 = bl + (size_t)(l * 2 + 0) * HDIM;
        const float* bl1 = bl + (size_t)(l * 2 + 1) * HDIM;

        // project-first for the device direction: ps = hs_in @ Wl0 (no bias)
        gemm_plain<<<GP, 256, 0, stream>>>(hs_in, WlT0, ps, NSRV, MB_P);
        // dev dsts gather ps; srv dsts gather hd_in
        aggregate_both<<<(NDEV + NSRV + 3) / 4, 256, 0, stream>>>(
            ps, hd_in, off_d, cnt_d, src_d, off_s, cnt_s, src_s, agg_d, agg_s);
        // dev: relu(agg_d + hd@Wr0 + bl0); srv: relu(agg_s@Wl1 + hs@Wr1 + bl1)
        gemm_both<<<GD + GS, 512, 0, stream>>>(
            hd_in, hd_in, WrT0, WrT0, agg_d, bl0, hd_out, NDEV, MB_D, GD,
            agg_s, hs_in, WlT1, WrT1, bl1, hs_out, NSRV, MB_S);
    }

    int hi = (int)NTOT;
    while (hi > 4000 && (hi % 2 == 0)) {
        int lo = hi / 2;
        int nblk = (hi - lo + 255) / 256;
        expand_k<<<nblk, 256, 0, stream>>>(fout, lo, hi);
        hi = lo;
    }
    expand_final<<<1, 512, 0, stream>>>(fout, hi);
}